// Round 1
// baseline (1395.174 us; speedup 1.0000x reference)
//
#include <hip/hip_runtime.h>

#define B_ 4
#define C_ 256
#define T_ 8
#define HW_ 784
#define RC_ 64
#define TNH (T_*HW_)   // 6272
#define BT_ (B_*T_)    // 32
#define TEMP_INV 14.28571428571f  // 1/0.07

__device__ __forceinline__ float4 ld4s(const float* p) { return *(const float4*)p; }

// ---------------- conv1x1 GEMM: Y[b,o,t,n] = sum_c W[o,c] * X[b,c,t,n] ----------------
// MODE 0: plain.  MODE 1: Y = relu(acc) * aux.  MODE 2: Y = acc + aux.
template<int MODE>
__global__ __launch_bounds__(256) void k_conv1x1(
    const float* __restrict__ Wm, const float* __restrict__ X,
    float* __restrict__ Y, const float* __restrict__ aux,
    int M, int K, int mtiles)
{
    __shared__ float Ws[16][68];   // [c][o], padded
    __shared__ float Xs[16][64];   // [c][n]
    const int sl = blockIdx.y;
    const int b = sl >> 3, t = sl & 7;
    const int bx = blockIdx.x;
    const int mt = bx % mtiles;
    const int nt = bx / mtiles;
    const int o0 = mt * 64, n0 = nt * 64;
    const int tid = threadIdx.x;
    const int tx = tid & 15, ty = tid >> 4;
    const float* Xb = X + (b * K * T_ + t) * HW_;
    const int nl = tid & 63;
    const int cb = tid >> 6;
    const bool nok = (n0 + nl) < HW_;
    float acc[4][4] = {};
    for (int k0 = 0; k0 < K; k0 += 16) {
        __syncthreads();
        #pragma unroll
        for (int p = 0; p < 4; ++p) {
            int o = p * 16 + ty;
            Ws[tx][o] = Wm[(o0 + o) * K + k0 + tx];
        }
        #pragma unroll
        for (int p = 0; p < 4; ++p) {
            int c = p * 4 + cb;
            Xs[c][nl] = nok ? Xb[(k0 + c) * TNH + n0 + nl] : 0.f;
        }
        __syncthreads();
        #pragma unroll
        for (int kk = 0; kk < 16; ++kk) {
            float4 av = ld4s(&Ws[kk][ty * 4]);
            float4 bv = ld4s(&Xs[kk][tx * 4]);
            float a_[4] = {av.x, av.y, av.z, av.w};
            float b_[4] = {bv.x, bv.y, bv.z, bv.w};
            #pragma unroll
            for (int i = 0; i < 4; ++i)
                #pragma unroll
                for (int j = 0; j < 4; ++j)
                    acc[i][j] = fmaf(a_[i], b_[j], acc[i][j]);
        }
    }
    const int ybase = (b * M) * TNH + t * HW_;
    #pragma unroll
    for (int i = 0; i < 4; ++i) {
        const int o = o0 + ty * 4 + i;
        #pragma unroll
        for (int j = 0; j < 4; ++j) {
            const int n = n0 + tx * 4 + j;
            if (n < HW_) {
                const int idx = ybase + o * TNH + n;
                float v = acc[i][j];
                if (MODE == 1) v = fmaxf(v, 0.f) * aux[idx];
                else if (MODE == 2) v += aux[idx];
                Y[idx] = v;
            }
        }
    }
}

// ---------------- inverse norm over channels ----------------
__global__ __launch_bounds__(256) void k_invnorm(
    const float* __restrict__ x1, float* __restrict__ invn)
{
    __shared__ float sm[4][64];
    const int sl = blockIdx.y, b = sl >> 3, t = sl & 7;
    const int l = threadIdx.x & 63;
    const int cg = threadIdx.x >> 6;
    const int n = blockIdx.x * 64 + l;
    float s = 0.f;
    if (n < HW_) {
        const float* p = x1 + (b * C_ * T_ + t) * HW_ + n;
        for (int c = cg * 64; c < cg * 64 + 64; ++c) {
            const float v = p[c * TNH];
            s = fmaf(v, v, s);
        }
    }
    sm[cg][l] = s;
    __syncthreads();
    if (threadIdx.x < 64 && n < HW_) {
        const float tot = sm[0][l] + sm[1][l] + sm[2][l] + sm[3][l];
        invn[sl * HW_ + n] = 1.f / fmaxf(sqrtf(tot), 1e-12f);
    }
}

// ---------------- affinity row sum-exp: sumexp[s,b,t,n] = sum_m exp(<nx_n, nsh_m>/TEMP) ----------------
__global__ __launch_bounds__(256) void k_affinity(
    const float* __restrict__ x1, const float* __restrict__ invn,
    float* __restrict__ sumexp)
{
    __shared__ float As[C_][32];   // 32 KB, rows (n) resident with full K
    __shared__ float Bs[32][64];   // 8 KB, k-chunk of cols (m)
    const int nt = blockIdx.x;     // 25 row tiles of 32
    const int sl = blockIdx.y;     // 32 slices
    const int s  = blockIdx.z;     // 3 shifts: 0=prev,1=next,2=id
    const int b = sl >> 3, t = sl & 7;
    const int t2 = (s == 0) ? (t > 0 ? t - 1 : 0) : (s == 1) ? (t < 7 ? t + 1 : 7) : t;
    const int n0 = nt * 32;
    const int tid = threadIdx.x;
    {   // stage A (prescaled by invnorm)
        const int n = tid & 31;
        const int c0 = tid >> 5;   // 0..7
        const bool ok = (n0 + n) < HW_;
        const float inA = ok ? invn[sl * HW_ + n0 + n] : 0.f;
        const float* p = x1 + (b * C_ * T_ + t) * HW_ + n0 + n;
        #pragma unroll 8
        for (int pp = 0; pp < 32; ++pp) {
            const int c = pp * 8 + c0;
            As[c][n] = ok ? p[c * TNH] * inA : 0.f;
        }
    }
    const int tx = tid & 15, ty = tid >> 4;
    const int ml = tid & 63;
    const int cb = tid >> 6;
    const float* q0 = x1 + (b * C_ * T_ + t2) * HW_;
    const float* invB = invn + (b * T_ + t2) * HW_;
    float ssum[2] = {0.f, 0.f};
    for (int mt = 0; mt < 13; ++mt) {
        const int m0 = mt * 64;
        const bool mok = (m0 + ml) < HW_;
        const float inB = mok ? invB[m0 + ml] : 0.f;
        float acc[2][4] = {};
        for (int k0 = 0; k0 < C_; k0 += 32) {
            __syncthreads();
            #pragma unroll
            for (int pp = 0; pp < 8; ++pp) {
                const int cr = pp * 4 + cb;
                Bs[cr][ml] = mok ? q0[(k0 + cr) * TNH + m0 + ml] * inB : 0.f;
            }
            __syncthreads();
            #pragma unroll
            for (int kk = 0; kk < 32; ++kk) {
                const float a0 = As[k0 + kk][ty * 2];
                const float a1 = As[k0 + kk][ty * 2 + 1];
                const float4 bv = ld4s(&Bs[kk][tx * 4]);
                acc[0][0] = fmaf(a0, bv.x, acc[0][0]);
                acc[0][1] = fmaf(a0, bv.y, acc[0][1]);
                acc[0][2] = fmaf(a0, bv.z, acc[0][2]);
                acc[0][3] = fmaf(a0, bv.w, acc[0][3]);
                acc[1][0] = fmaf(a1, bv.x, acc[1][0]);
                acc[1][1] = fmaf(a1, bv.y, acc[1][1]);
                acc[1][2] = fmaf(a1, bv.z, acc[1][2]);
                acc[1][3] = fmaf(a1, bv.w, acc[1][3]);
            }
        }
        #pragma unroll
        for (int j = 0; j < 4; ++j) {
            if (m0 + tx * 4 + j < HW_) {
                ssum[0] += __expf(acc[0][j] * TEMP_INV);
                ssum[1] += __expf(acc[1][j] * TEMP_INV);
            }
        }
    }
    #pragma unroll
    for (int i = 0; i < 2; ++i) {
        float v = ssum[i];
        v += __shfl_xor(v, 1, 16);
        v += __shfl_xor(v, 2, 16);
        v += __shfl_xor(v, 4, 16);
        v += __shfl_xor(v, 8, 16);
        if (tx == 0) {
            const int row = n0 + ty * 2 + i;
            if (row < HW_) sumexp[(s * BT_ + sl) * HW_ + row] = v;
        }
    }
}

// ---------------- diagonal similarity + diag_sm = exp(diag)/sumexp ----------------
__global__ __launch_bounds__(256) void k_diagsm(
    const float* __restrict__ x1, const float* __restrict__ invn,
    const float* __restrict__ sumexp, float* __restrict__ dsm)
{
    __shared__ float sm[3][4][64];
    const int sl = blockIdx.y, b = sl >> 3, t = sl & 7;
    const int l = threadIdx.x & 63;
    const int cg = threadIdx.x >> 6;
    const int n = blockIdx.x * 64 + l;
    const int tp = t > 0 ? t - 1 : 0;
    const int tn = t < 7 ? t + 1 : 7;
    float sp = 0.f, sn2 = 0.f, si = 0.f;
    if (n < HW_) {
        const float* p0 = x1 + (b * C_ * T_ + t) * HW_ + n;
        const float* pp = x1 + (b * C_ * T_ + tp) * HW_ + n;
        const float* pn = x1 + (b * C_ * T_ + tn) * HW_ + n;
        for (int c = cg * 64; c < cg * 64 + 64; ++c) {
            const float v = p0[c * TNH];
            sp  = fmaf(v, pp[c * TNH], sp);
            sn2 = fmaf(v, pn[c * TNH], sn2);
            si  = fmaf(v, v, si);
        }
    }
    sm[0][cg][l] = sp; sm[1][cg][l] = sn2; sm[2][cg][l] = si;
    __syncthreads();
    if (threadIdx.x < 64 && n < HW_) {
        const float d0 = sm[0][0][l] + sm[0][1][l] + sm[0][2][l] + sm[0][3][l];
        const float d1 = sm[1][0][l] + sm[1][1][l] + sm[1][2][l] + sm[1][3][l];
        const float d2 = sm[2][0][l] + sm[2][1][l] + sm[2][2][l] + sm[2][3][l];
        const float it  = invn[sl * HW_ + n];
        const float ip  = invn[(b * T_ + tp) * HW_ + n];
        const float in2 = invn[(b * T_ + tn) * HW_ + n];
        dsm[(0 * BT_ + sl) * HW_ + n] = __expf(d0 * it * ip  * TEMP_INV) / sumexp[(0 * BT_ + sl) * HW_ + n];
        dsm[(1 * BT_ + sl) * HW_ + n] = __expf(d1 * it * in2 * TEMP_INV) / sumexp[(1 * BT_ + sl) * HW_ + n];
        dsm[(2 * BT_ + sl) * HW_ + n] = __expf(d2 * it * it  * TEMP_INV) / sumexp[(2 * BT_ + sl) * HW_ + n];
    }
}

// ---------------- feats blend ----------------
__global__ __launch_bounds__(256) void k_feats(
    const float* __restrict__ x1, const float* __restrict__ dsm,
    float* __restrict__ feats)
{
    const int bct = blockIdx.x;
    const int t = bct & 7;
    const int c = (bct >> 3) & 255;
    const int b = bct >> 11;
    const int tp = t > 0 ? t - 1 : 0;
    const int tn = t < 7 ? t + 1 : 7;
    const int base = (b * C_ + c) * TNH;
    const float* dp = dsm + (0 * BT_ + b * T_ + t) * HW_;
    const float* dn = dsm + (1 * BT_ + b * T_ + t) * HW_;
    const float* di = dsm + (2 * BT_ + b * T_ + t) * HW_;
    const float* xp = x1 + base + tp * HW_;
    const float* xn = x1 + base + tn * HW_;
    const float* xi = x1 + base + t * HW_;
    float* fo = feats + base + t * HW_;
    for (int n = threadIdx.x; n < HW_; n += 256) {
        fo[n] = (dp[n] * xp[n] + dn[n] * xn[n] + di[n] * xi[n]) * (1.f / 3.f);
    }
}

// ---------------- depthwise 3D conv, 3 dilations fused ----------------
__global__ __launch_bounds__(256) void k_dwconv(
    const float* __restrict__ xx, const float* __restrict__ Wsa1,
    const float* __restrict__ Wsa2, const float* __restrict__ Wsa3,
    float* __restrict__ agg)
{
    __shared__ float pl[9][HW_];
    __shared__ float wl[3][81];
    const int idx = blockIdx.x;    // (b*RC + r)*T + t
    const int t = idx & 7;
    const int br = idx >> 3;
    const int r = br & 63;
    const int tid = threadIdx.x;
    const int base = br * TNH;
    for (int kt = 0; kt < 9; ++kt) {
        const int ts = t + kt - 4;
        if (ts >= 0 && ts < 8) {
            for (int i = tid; i < HW_; i += 256) pl[kt][i] = xx[base + ts * HW_ + i];
        } else {
            for (int i = tid; i < HW_; i += 256) pl[kt][i] = 0.f;
        }
    }
    if (tid < 81) {
        wl[0][tid] = Wsa1[r * 81 + tid] * (1.f / 3.f);
        wl[1][tid] = Wsa2[r * 81 + tid] * (1.f / 3.f);
        wl[2][tid] = Wsa3[r * 81 + tid] * (1.f / 3.f);
    }
    __syncthreads();
    for (int p = tid; p < HW_; p += 256) {
        const int h = p / 28, w = p % 28;
        float acc = 0.f;
        #pragma unroll
        for (int s = 0; s < 3; ++s) {
            const int d = s + 1;
            for (int kt = 0; kt < 9; ++kt) {
                #pragma unroll
                for (int kh = 0; kh < 3; ++kh) {
                    const int hh = h + (kh - 1) * d;
                    if (hh < 0 || hh >= 28) continue;
                    #pragma unroll
                    for (int kw = 0; kw < 3; ++kw) {
                        const int ww = w + (kw - 1) * d;
                        if (ww < 0 || ww >= 28) continue;
                        acc = fmaf(pl[kt][hh * 28 + ww], wl[s][kt * 9 + kh * 3 + kw], acc);
                    }
                }
            }
        }
        agg[base + t * HW_ + p] = acc;
    }
}

// ---------------- BN stats per channel ----------------
__global__ __launch_bounds__(256) void k_bnstats(
    const float* __restrict__ y, const float* __restrict__ gamma,
    const float* __restrict__ beta, float* __restrict__ stats)
{
    __shared__ float sm1[256], sm2[256];
    const int c = blockIdx.x;
    float s1 = 0.f, s2 = 0.f;
    for (int b = 0; b < B_; ++b) {
        const float* p = y + (b * C_ + c) * TNH;
        for (int i = threadIdx.x; i < TNH; i += 256) {
            const float v = p[i];
            s1 += v; s2 = fmaf(v, v, s2);
        }
    }
    sm1[threadIdx.x] = s1; sm2[threadIdx.x] = s2;
    __syncthreads();
    for (int off = 128; off > 0; off >>= 1) {
        if (threadIdx.x < off) {
            sm1[threadIdx.x] += sm1[threadIdx.x + off];
            sm2[threadIdx.x] += sm2[threadIdx.x + off];
        }
        __syncthreads();
    }
    if (threadIdx.x == 0) {
        const float M = (float)(B_ * TNH);
        const float mean = sm1[0] / M;
        const float var = sm2[0] / M - mean * mean;
        const float sc = gamma[c] * rsqrtf(var + 1e-5f);
        stats[c] = sc;
        stats[C_ + c] = beta[c] - mean * sc;
    }
}

// ---------------- BN apply + relu ----------------
__global__ __launch_bounds__(256) void k_bnapply(
    const float* __restrict__ y, const float* __restrict__ stats,
    float* __restrict__ out)
{
    const int total4 = B_ * C_ * TNH / 4;
    for (int i4 = blockIdx.x * 256 + threadIdx.x; i4 < total4; i4 += gridDim.x * 256) {
        float4 v = ((const float4*)y)[i4];
        const int c = (i4 / (TNH / 4)) & 255;
        const float sc = stats[c], bi = stats[C_ + c];
        v.x = fmaxf(fmaf(v.x, sc, bi), 0.f);
        v.y = fmaxf(fmaf(v.y, sc, bi), 0.f);
        v.z = fmaxf(fmaf(v.z, sc, bi), 0.f);
        v.w = fmaxf(fmaf(v.w, sc, bi), 0.f);
        ((float4*)out)[i4] = v;
    }
}

extern "C" void kernel_launch(void* const* d_in, const int* in_sizes, int n_in,
                              void* d_out, int out_size, void* d_ws, size_t ws_size,
                              hipStream_t stream) {
    (void)in_sizes; (void)n_in; (void)out_size; (void)ws_size;
    const float* x      = (const float*)d_in[0];
    const float* W_dc2  = (const float*)d_in[1];
    const float* W_up2  = (const float*)d_in[2];
    const float* W_dc   = (const float*)d_in[3];
    const float* Wsa1   = (const float*)d_in[4];
    const float* Wsa2   = (const float*)d_in[5];
    const float* Wsa3   = (const float*)d_in[6];
    const float* W_back = (const float*)d_in[7];
    const float* gamma  = (const float*)d_in[8];
    const float* beta   = (const float*)d_in[9];
    float* out = (float*)d_out;
    float* ws  = (float*)d_ws;

    const size_t NE = (size_t)B_ * C_ * TNH;       // 6,422,528
    float* x1     = ws;                            // x1, later fs
    float* buf2   = ws + NE;                       // feats, later y
    float* xx     = ws + 2 * NE;                   // 1,605,632
    float* agg    = xx + (size_t)B_ * RC_ * TNH;
    float* invn   = agg + (size_t)B_ * RC_ * TNH;  // 25,088
    float* sumexp = invn + (size_t)BT_ * HW_;      // 3*25,088
    float* dsm    = sumexp + 3 * (size_t)BT_ * HW_;
    float* stats  = dsm + 3 * (size_t)BT_ * HW_;   // 512

    // 1. x1 = W_dc2 @ x
    k_conv1x1<0><<<dim3(4 * 13, 32), 256, 0, stream>>>(W_dc2, x, x1, nullptr, 256, 256, 4);
    // 2. invnorm
    k_invnorm<<<dim3(13, 32), 256, 0, stream>>>(x1, invn);
    // 3. affinity sum-exp for 3 shifts
    k_affinity<<<dim3(25, 32, 3), 256, 0, stream>>>(x1, invn, sumexp);
    // 4. diag_sm
    k_diagsm<<<dim3(13, 32), 256, 0, stream>>>(x1, invn, sumexp, dsm);
    // 5. feats blend -> buf2
    k_feats<<<8192, 256, 0, stream>>>(x1, dsm, buf2);
    // 6. xx = W_dc @ x1
    k_conv1x1<0><<<dim3(1 * 13, 32), 256, 0, stream>>>(W_dc, x1, xx, nullptr, 64, 256, 1);
    // 7. agg = mean of 3 dilated dwconvs
    k_dwconv<<<2048, 256, 0, stream>>>(xx, Wsa1, Wsa2, Wsa3, agg);
    // 8. fs = relu(W_back @ agg) * feats -> overwrite x1 buffer
    k_conv1x1<1><<<dim3(4 * 13, 32), 256, 0, stream>>>(W_back, agg, x1, buf2, 256, 64, 4);
    // 9. y = x + W_up2 @ fs -> buf2
    k_conv1x1<2><<<dim3(4 * 13, 32), 256, 0, stream>>>(W_up2, x1, buf2, x, 256, 256, 4);
    // 10. BN stats
    k_bnstats<<<256, 256, 0, stream>>>(buf2, gamma, beta, stats);
    // 11. BN apply + relu -> out
    k_bnapply<<<2048, 256, 0, stream>>>(buf2, stats, out);
}

// Round 2
// 805.837 us; speedup vs baseline: 1.7313x; 1.7313x over previous
//
#include <hip/hip_runtime.h>

#define B_ 4
#define C_ 256
#define T_ 8
#define HW_ 784
#define RC_ 64
#define TNH (T_*HW_)   // 6272
#define BT_ (B_*T_)    // 32
#define TEMP_INV 14.28571428571f  // 1/0.07

typedef __attribute__((ext_vector_type(8))) short bf16x8;
typedef __attribute__((ext_vector_type(4))) float f32x4;

__device__ __forceinline__ float4 ld4s(const float* p) { return *(const float4*)p; }

__device__ __forceinline__ ushort f2bf(float f) {
    uint x = __float_as_uint(f);
    uint r = (x + 0x7FFFu + ((x >> 16) & 1u)) >> 16;   // RNE
    return (ushort)r;
}

// ---------------- conv1x1 GEMM: Y[b,o,t,n] = sum_c W[o,c] * X[b,c,t,n] ----------------
// MODE 0: plain.  MODE 1: Y = relu(acc) * aux.  MODE 2: Y = acc + aux.
template<int MODE>
__global__ __launch_bounds__(256) void k_conv1x1(
    const float* __restrict__ Wm, const float* __restrict__ X,
    float* __restrict__ Y, const float* __restrict__ aux,
    int M, int K, int mtiles)
{
    __shared__ float Ws[16][68];   // [c][o], padded
    __shared__ float Xs[16][64];   // [c][n]
    const int sl = blockIdx.y;
    const int b = sl >> 3, t = sl & 7;
    const int bx = blockIdx.x;
    const int mt = bx % mtiles;
    const int nt = bx / mtiles;
    const int o0 = mt * 64, n0 = nt * 64;
    const int tid = threadIdx.x;
    const int tx = tid & 15, ty = tid >> 4;
    const float* Xb = X + (b * K * T_ + t) * HW_;
    const int nl = tid & 63;
    const int cb = tid >> 6;
    const bool nok = (n0 + nl) < HW_;
    float acc[4][4] = {};
    for (int k0 = 0; k0 < K; k0 += 16) {
        __syncthreads();
        #pragma unroll
        for (int p = 0; p < 4; ++p) {
            int o = p * 16 + ty;
            Ws[tx][o] = Wm[(o0 + o) * K + k0 + tx];
        }
        #pragma unroll
        for (int p = 0; p < 4; ++p) {
            int c = p * 4 + cb;
            Xs[c][nl] = nok ? Xb[(k0 + c) * TNH + n0 + nl] : 0.f;
        }
        __syncthreads();
        #pragma unroll
        for (int kk = 0; kk < 16; ++kk) {
            float4 av = ld4s(&Ws[kk][ty * 4]);
            float4 bv = ld4s(&Xs[kk][tx * 4]);
            float a_[4] = {av.x, av.y, av.z, av.w};
            float b_[4] = {bv.x, bv.y, bv.z, bv.w};
            #pragma unroll
            for (int i = 0; i < 4; ++i)
                #pragma unroll
                for (int j = 0; j < 4; ++j)
                    acc[i][j] = fmaf(a_[i], b_[j], acc[i][j]);
        }
    }
    const int ybase = (b * M) * TNH + t * HW_;
    #pragma unroll
    for (int i = 0; i < 4; ++i) {
        const int o = o0 + ty * 4 + i;
        #pragma unroll
        for (int j = 0; j < 4; ++j) {
            const int n = n0 + tx * 4 + j;
            if (n < HW_) {
                const int idx = ybase + o * TNH + n;
                float v = acc[i][j];
                if (MODE == 1) v = fmaxf(v, 0.f) * aux[idx];
                else if (MODE == 2) v += aux[idx];
                Y[idx] = v;
            }
        }
    }
}

// ---------------- inverse norm over channels ----------------
__global__ __launch_bounds__(256) void k_invnorm(
    const float* __restrict__ x1, float* __restrict__ invn)
{
    __shared__ float sm[4][64];
    const int sl = blockIdx.y, b = sl >> 3, t = sl & 7;
    const int l = threadIdx.x & 63;
    const int cg = threadIdx.x >> 6;
    const int n = blockIdx.x * 64 + l;
    float s = 0.f;
    if (n < HW_) {
        const float* p = x1 + (b * C_ * T_ + t) * HW_ + n;
        for (int c = cg * 64; c < cg * 64 + 64; ++c) {
            const float v = p[c * TNH];
            s = fmaf(v, v, s);
        }
    }
    sm[cg][l] = s;
    __syncthreads();
    if (threadIdx.x < 64 && n < HW_) {
        const float tot = sm[0][l] + sm[1][l] + sm[2][l] + sm[3][l];
        invn[sl * HW_ + n] = 1.f / fmaxf(sqrtf(tot), 1e-12f);
    }
}

// ---------------- nxT: bf16 normalized features, transposed [sl][n][c] ----------------
__global__ __launch_bounds__(256) void k_nxT(
    const float* __restrict__ x1, const float* __restrict__ invn,
    ushort* __restrict__ nxT)
{
    __shared__ float xs[256][17];
    __shared__ float inv_s[16];
    const int sl = blockIdx.y, b = sl >> 3, t = sl & 7;
    const int n0 = blockIdx.x * 16;    // 49 blocks, 784 = 49*16 exact
    const int tid = threadIdx.x;
    {
        const int n_l = tid & 15;
        const int c0 = tid >> 4;       // 0..15
        const float* p = x1 + (b * C_ * T_ + c0 * T_ + t) * HW_ + n0 + n_l;
        #pragma unroll
        for (int i = 0; i < 16; ++i)
            xs[c0 + 16 * i][n_l] = p[(size_t)16 * i * TNH];
        if (tid < 16) inv_s[tid] = invn[sl * HW_ + n0 + tid];
    }
    __syncthreads();
    const int n_l = tid >> 4;
    const int cq = tid & 15;
    const float inv = inv_s[n_l];
    union { ushort u[16]; uint4 q[2]; } o;
    #pragma unroll
    for (int i = 0; i < 16; ++i)
        o.u[i] = f2bf(xs[cq * 16 + i][n_l] * inv);
    uint4* dst = (uint4*)(nxT + ((size_t)(sl * HW_ + n0 + n_l)) * 256 + cq * 16);
    dst[0] = o.q[0];
    dst[1] = o.q[1];
}

// ---------------- affinity row sum-exp via MFMA ----------------
// sumexp[s,sl,n] = sum_m exp(<nx[:,n], nx_sh[:,m]> / TEMP)
__global__ __launch_bounds__(256) void k_affinity_mfma(
    const ushort* __restrict__ nxT, float* __restrict__ sumexp)
{
    const int sl = blockIdx.y;           // 32
    const int s  = blockIdx.z;           // 3 shifts: 0=prev,1=next,2=id
    const int b = sl >> 3, t = sl & 7;
    const int t2 = (s == 0) ? (t > 0 ? t - 1 : 0) : (s == 1) ? (t < 7 ? t + 1 : 7) : t;
    const int sl2 = b * 8 + t2;
    const int wid = threadIdx.x >> 6;
    const int lane = threadIdx.x & 63;
    const int rt = blockIdx.x * 4 + wid; // row tile 0..48
    if (rt >= 49) return;
    const int n0 = rt * 16;
    const int r  = lane & 15;
    const int kg = lane >> 4;            // 0..3
    // A fragments: rows n0+r, k = kk*32 + kg*8 + [0..7]  (8 frags resident)
    const short* Abase = (const short*)nxT + ((size_t)sl * HW_ + n0 + r) * 256 + kg * 8;
    bf16x8 a[8];
    #pragma unroll
    for (int kk = 0; kk < 8; ++kk)
        a[kk] = *(const bf16x8*)(Abase + kk * 32);
    const short* Bbase = (const short*)nxT + (size_t)sl2 * HW_ * 256 + r * 256 + kg * 8;
    float re[4] = {0.f, 0.f, 0.f, 0.f};
    for (int mt = 0; mt < 49; ++mt) {
        f32x4 acc = {0.f, 0.f, 0.f, 0.f};
        const short* Bp = Bbase + (size_t)mt * 16 * 256;
        #pragma unroll
        for (int kk = 0; kk < 8; ++kk) {
            bf16x8 bfr = *(const bf16x8*)(Bp + kk * 32);
            acc = __builtin_amdgcn_mfma_f32_16x16x32_bf16(a[kk], bfr, acc, 0, 0, 0);
        }
        #pragma unroll
        for (int j = 0; j < 4; ++j)
            re[j] += __expf(acc[j] * TEMP_INV);
    }
    // D layout: col(m) = lane&15, row(n) = kg*4 + j.  Sum over m: reduce 16-lane group.
    #pragma unroll
    for (int j = 0; j < 4; ++j) {
        float v = re[j];
        v += __shfl_xor(v, 1);
        v += __shfl_xor(v, 2);
        v += __shfl_xor(v, 4);
        v += __shfl_xor(v, 8);
        re[j] = v;
    }
    if ((lane & 15) == 0) {
        #pragma unroll
        for (int j = 0; j < 4; ++j)
            sumexp[(s * BT_ + sl) * HW_ + n0 + kg * 4 + j] = re[j];
    }
}

// ---------------- diagonal similarity + diag_sm = exp(diag)/sumexp ----------------
__global__ __launch_bounds__(256) void k_diagsm(
    const float* __restrict__ x1, const float* __restrict__ invn,
    const float* __restrict__ sumexp, float* __restrict__ dsm)
{
    __shared__ float sm[3][4][64];
    const int sl = blockIdx.y, b = sl >> 3, t = sl & 7;
    const int l = threadIdx.x & 63;
    const int cg = threadIdx.x >> 6;
    const int n = blockIdx.x * 64 + l;
    const int tp = t > 0 ? t - 1 : 0;
    const int tn = t < 7 ? t + 1 : 7;
    float sp = 0.f, sn2 = 0.f, si = 0.f;
    if (n < HW_) {
        const float* p0 = x1 + (b * C_ * T_ + t) * HW_ + n;
        const float* pp = x1 + (b * C_ * T_ + tp) * HW_ + n;
        const float* pn = x1 + (b * C_ * T_ + tn) * HW_ + n;
        for (int c = cg * 64; c < cg * 64 + 64; ++c) {
            const float v = p0[c * TNH];
            sp  = fmaf(v, pp[c * TNH], sp);
            sn2 = fmaf(v, pn[c * TNH], sn2);
            si  = fmaf(v, v, si);
        }
    }
    sm[0][cg][l] = sp; sm[1][cg][l] = sn2; sm[2][cg][l] = si;
    __syncthreads();
    if (threadIdx.x < 64 && n < HW_) {
        const float d0 = sm[0][0][l] + sm[0][1][l] + sm[0][2][l] + sm[0][3][l];
        const float d1 = sm[1][0][l] + sm[1][1][l] + sm[1][2][l] + sm[1][3][l];
        const float d2 = sm[2][0][l] + sm[2][1][l] + sm[2][2][l] + sm[2][3][l];
        const float it  = invn[sl * HW_ + n];
        const float ip  = invn[(b * T_ + tp) * HW_ + n];
        const float in2 = invn[(b * T_ + tn) * HW_ + n];
        dsm[(0 * BT_ + sl) * HW_ + n] = __expf(d0 * it * ip  * TEMP_INV) / sumexp[(0 * BT_ + sl) * HW_ + n];
        dsm[(1 * BT_ + sl) * HW_ + n] = __expf(d1 * it * in2 * TEMP_INV) / sumexp[(1 * BT_ + sl) * HW_ + n];
        dsm[(2 * BT_ + sl) * HW_ + n] = __expf(d2 * it * it  * TEMP_INV) / sumexp[(2 * BT_ + sl) * HW_ + n];
    }
}

// ---------------- feats blend ----------------
__global__ __launch_bounds__(256) void k_feats(
    const float* __restrict__ x1, const float* __restrict__ dsm,
    float* __restrict__ feats)
{
    const int bct = blockIdx.x;
    const int t = bct & 7;
    const int c = (bct >> 3) & 255;
    const int b = bct >> 11;
    const int tp = t > 0 ? t - 1 : 0;
    const int tn = t < 7 ? t + 1 : 7;
    const int base = (b * C_ + c) * TNH;
    const float* dp = dsm + (0 * BT_ + b * T_ + t) * HW_;
    const float* dn = dsm + (1 * BT_ + b * T_ + t) * HW_;
    const float* di = dsm + (2 * BT_ + b * T_ + t) * HW_;
    const float* xp = x1 + base + tp * HW_;
    const float* xn = x1 + base + tn * HW_;
    const float* xi = x1 + base + t * HW_;
    float* fo = feats + base + t * HW_;
    for (int n = threadIdx.x; n < HW_; n += 256) {
        fo[n] = (dp[n] * xp[n] + dn[n] * xn[n] + di[n] * xi[n]) * (1.f / 3.f);
    }
}

// ---------------- depthwise 3D conv, 3 dilations fused ----------------
__global__ __launch_bounds__(256) void k_dwconv(
    const float* __restrict__ xx, const float* __restrict__ Wsa1,
    const float* __restrict__ Wsa2, const float* __restrict__ Wsa3,
    float* __restrict__ agg)
{
    __shared__ float pl[9][HW_];
    __shared__ float wl[3][81];
    const int idx = blockIdx.x;    // (b*RC + r)*T + t
    const int t = idx & 7;
    const int br = idx >> 3;
    const int r = br & 63;
    const int tid = threadIdx.x;
    const int base = br * TNH;
    for (int kt = 0; kt < 9; ++kt) {
        const int ts = t + kt - 4;
        if (ts >= 0 && ts < 8) {
            for (int i = tid; i < HW_; i += 256) pl[kt][i] = xx[base + ts * HW_ + i];
        } else {
            for (int i = tid; i < HW_; i += 256) pl[kt][i] = 0.f;
        }
    }
    if (tid < 81) {
        wl[0][tid] = Wsa1[r * 81 + tid] * (1.f / 3.f);
        wl[1][tid] = Wsa2[r * 81 + tid] * (1.f / 3.f);
        wl[2][tid] = Wsa3[r * 81 + tid] * (1.f / 3.f);
    }
    __syncthreads();
    for (int p = tid; p < HW_; p += 256) {
        const int h = p / 28, w = p % 28;
        float acc = 0.f;
        #pragma unroll
        for (int s = 0; s < 3; ++s) {
            const int d = s + 1;
            for (int kt = 0; kt < 9; ++kt) {
                #pragma unroll
                for (int kh = 0; kh < 3; ++kh) {
                    const int hh = h + (kh - 1) * d;
                    if (hh < 0 || hh >= 28) continue;
                    #pragma unroll
                    for (int kw = 0; kw < 3; ++kw) {
                        const int ww = w + (kw - 1) * d;
                        if (ww < 0 || ww >= 28) continue;
                        acc = fmaf(pl[kt][hh * 28 + ww], wl[s][kt * 9 + kh * 3 + kw], acc);
                    }
                }
            }
        }
        agg[base + t * HW_ + p] = acc;
    }
}

// ---------------- BN stats per channel ----------------
__global__ __launch_bounds__(256) void k_bnstats(
    const float* __restrict__ y, const float* __restrict__ gamma,
    const float* __restrict__ beta, float* __restrict__ stats)
{
    __shared__ float sm1[256], sm2[256];
    const int c = blockIdx.x;
    float s1 = 0.f, s2 = 0.f;
    for (int b = 0; b < B_; ++b) {
        const float* p = y + (b * C_ + c) * TNH;
        for (int i = threadIdx.x; i < TNH; i += 256) {
            const float v = p[i];
            s1 += v; s2 = fmaf(v, v, s2);
        }
    }
    sm1[threadIdx.x] = s1; sm2[threadIdx.x] = s2;
    __syncthreads();
    for (int off = 128; off > 0; off >>= 1) {
        if (threadIdx.x < off) {
            sm1[threadIdx.x] += sm1[threadIdx.x + off];
            sm2[threadIdx.x] += sm2[threadIdx.x + off];
        }
        __syncthreads();
    }
    if (threadIdx.x == 0) {
        const float M = (float)(B_ * TNH);
        const float mean = sm1[0] / M;
        const float var = sm2[0] / M - mean * mean;
        const float sc = gamma[c] * rsqrtf(var + 1e-5f);
        stats[c] = sc;
        stats[C_ + c] = beta[c] - mean * sc;
    }
}

// ---------------- BN apply + relu ----------------
__global__ __launch_bounds__(256) void k_bnapply(
    const float* __restrict__ y, const float* __restrict__ stats,
    float* __restrict__ out)
{
    const int total4 = B_ * C_ * TNH / 4;
    for (int i4 = blockIdx.x * 256 + threadIdx.x; i4 < total4; i4 += gridDim.x * 256) {
        float4 v = ((const float4*)y)[i4];
        const int c = (i4 / (TNH / 4)) & 255;
        const float sc = stats[c], bi = stats[C_ + c];
        v.x = fmaxf(fmaf(v.x, sc, bi), 0.f);
        v.y = fmaxf(fmaf(v.y, sc, bi), 0.f);
        v.z = fmaxf(fmaf(v.z, sc, bi), 0.f);
        v.w = fmaxf(fmaf(v.w, sc, bi), 0.f);
        ((float4*)out)[i4] = v;
    }
}

extern "C" void kernel_launch(void* const* d_in, const int* in_sizes, int n_in,
                              void* d_out, int out_size, void* d_ws, size_t ws_size,
                              hipStream_t stream) {
    (void)in_sizes; (void)n_in; (void)out_size; (void)ws_size;
    const float* x      = (const float*)d_in[0];
    const float* W_dc2  = (const float*)d_in[1];
    const float* W_up2  = (const float*)d_in[2];
    const float* W_dc   = (const float*)d_in[3];
    const float* Wsa1   = (const float*)d_in[4];
    const float* Wsa2   = (const float*)d_in[5];
    const float* Wsa3   = (const float*)d_in[6];
    const float* W_back = (const float*)d_in[7];
    const float* gamma  = (const float*)d_in[8];
    const float* beta   = (const float*)d_in[9];
    float* out = (float*)d_out;
    float* ws  = (float*)d_ws;

    const size_t NE = (size_t)B_ * C_ * TNH;       // 6,422,528
    float* x1     = ws;                            // x1, later fs
    float* buf2   = ws + NE;                       // nxT (bf16 alias), then feats, then y
    float* xx     = ws + 2 * NE;                   // 1,605,632
    float* agg    = xx + (size_t)B_ * RC_ * TNH;
    float* invn   = agg + (size_t)B_ * RC_ * TNH;  // 25,088
    float* sumexp = invn + (size_t)BT_ * HW_;      // 3*25,088
    float* dsm    = sumexp + 3 * (size_t)BT_ * HW_;
    float* stats  = dsm + 3 * (size_t)BT_ * HW_;   // 512
    ushort* nxT   = (ushort*)buf2;                 // 12.8 MB bf16, dead after k_affinity_mfma

    // 1. x1 = W_dc2 @ x
    k_conv1x1<0><<<dim3(4 * 13, 32), 256, 0, stream>>>(W_dc2, x, x1, nullptr, 256, 256, 4);
    // 2. invnorm
    k_invnorm<<<dim3(13, 32), 256, 0, stream>>>(x1, invn);
    // 3. nxT = bf16(x1 * invn), transposed to [sl][n][c]
    k_nxT<<<dim3(49, 32), 256, 0, stream>>>(x1, invn, nxT);
    // 4. affinity sum-exp for 3 shifts (MFMA)
    k_affinity_mfma<<<dim3(13, 32, 3), 256, 0, stream>>>(nxT, sumexp);
    // 5. diag_sm
    k_diagsm<<<dim3(13, 32), 256, 0, stream>>>(x1, invn, sumexp, dsm);
    // 6. feats blend -> buf2 (overwrites nxT, which is now dead)
    k_feats<<<8192, 256, 0, stream>>>(x1, dsm, buf2);
    // 7. xx = W_dc @ x1
    k_conv1x1<0><<<dim3(1 * 13, 32), 256, 0, stream>>>(W_dc, x1, xx, nullptr, 64, 256, 1);
    // 8. agg = mean of 3 dilated dwconvs
    k_dwconv<<<2048, 256, 0, stream>>>(xx, Wsa1, Wsa2, Wsa3, agg);
    // 9. fs = relu(W_back @ agg) * feats -> overwrite x1 buffer
    k_conv1x1<1><<<dim3(4 * 13, 32), 256, 0, stream>>>(W_back, agg, x1, buf2, 256, 64, 4);
    // 10. y = x + W_up2 @ fs -> buf2
    k_conv1x1<2><<<dim3(4 * 13, 32), 256, 0, stream>>>(W_up2, x1, buf2, x, 256, 256, 4);
    // 11. BN stats
    k_bnstats<<<256, 256, 0, stream>>>(buf2, gamma, beta, stats);
    // 12. BN apply + relu -> out
    k_bnapply<<<2048, 256, 0, stream>>>(buf2, stats, out);
}

// Round 3
// 606.629 us; speedup vs baseline: 2.2999x; 1.3284x over previous
//
#include <hip/hip_runtime.h>

#define B_ 4
#define C_ 256
#define T_ 8
#define HW_ 784
#define RC_ 64
#define TNH (T_*HW_)   // 6272
#define BT_ (B_*T_)    // 32
#define TEMP_INV 14.28571428571f  // 1/0.07

typedef __attribute__((ext_vector_type(8))) short bf16x8;
typedef __attribute__((ext_vector_type(4))) float f32x4;

__device__ __forceinline__ float4 ld4s(const float* p) { return *(const float4*)p; }

__device__ __forceinline__ ushort f2bf(float f) {
    uint x = __float_as_uint(f);
    uint r = (x + 0x7FFFu + ((x >> 16) & 1u)) >> 16;   // RNE
    return (ushort)r;
}

// ---------------- conv1x1 GEMM: Y[b,o,t,n] = sum_c W[o,c] * X[b,c,t,n] ----------------
// MODE 0: plain.  MODE 1: Y = relu(acc) * aux.  MODE 2: Y = acc + aux.
template<int MODE>
__global__ __launch_bounds__(256) void k_conv1x1(
    const float* __restrict__ Wm, const float* __restrict__ X,
    float* __restrict__ Y, const float* __restrict__ aux,
    int M, int K, int mtiles)
{
    __shared__ float Ws[16][68];   // [c][o], padded
    __shared__ float Xs[16][64];   // [c][n]
    const int sl = blockIdx.y;
    const int b = sl >> 3, t = sl & 7;
    const int bx = blockIdx.x;
    const int mt = bx % mtiles;
    const int nt = bx / mtiles;
    const int o0 = mt * 64, n0 = nt * 64;
    const int tid = threadIdx.x;
    const int tx = tid & 15, ty = tid >> 4;
    const float* Xb = X + (b * K * T_ + t) * HW_;
    const int nl = tid & 63;
    const int cb = tid >> 6;
    const bool nok = (n0 + nl) < HW_;
    float acc[4][4] = {};
    for (int k0 = 0; k0 < K; k0 += 16) {
        __syncthreads();
        #pragma unroll
        for (int p = 0; p < 4; ++p) {
            int o = p * 16 + ty;
            Ws[tx][o] = Wm[(o0 + o) * K + k0 + tx];
        }
        #pragma unroll
        for (int p = 0; p < 4; ++p) {
            int c = p * 4 + cb;
            Xs[c][nl] = nok ? Xb[(k0 + c) * TNH + n0 + nl] : 0.f;
        }
        __syncthreads();
        #pragma unroll
        for (int kk = 0; kk < 16; ++kk) {
            float4 av = ld4s(&Ws[kk][ty * 4]);
            float4 bv = ld4s(&Xs[kk][tx * 4]);
            float a_[4] = {av.x, av.y, av.z, av.w};
            float b_[4] = {bv.x, bv.y, bv.z, bv.w};
            #pragma unroll
            for (int i = 0; i < 4; ++i)
                #pragma unroll
                for (int j = 0; j < 4; ++j)
                    acc[i][j] = fmaf(a_[i], b_[j], acc[i][j]);
        }
    }
    const int ybase = (b * M) * TNH + t * HW_;
    #pragma unroll
    for (int i = 0; i < 4; ++i) {
        const int o = o0 + ty * 4 + i;
        #pragma unroll
        for (int j = 0; j < 4; ++j) {
            const int n = n0 + tx * 4 + j;
            if (n < HW_) {
                const int idx = ybase + o * TNH + n;
                float v = acc[i][j];
                if (MODE == 1) v = fmaxf(v, 0.f) * aux[idx];
                else if (MODE == 2) v += aux[idx];
                Y[idx] = v;
            }
        }
    }
}

// ---------------- inverse norm over channels ----------------
__global__ __launch_bounds__(256) void k_invnorm(
    const float* __restrict__ x1, float* __restrict__ invn)
{
    __shared__ float sm[4][64];
    const int sl = blockIdx.y, b = sl >> 3, t = sl & 7;
    const int l = threadIdx.x & 63;
    const int cg = threadIdx.x >> 6;
    const int n = blockIdx.x * 64 + l;
    float s = 0.f;
    if (n < HW_) {
        const float* p = x1 + (b * C_ * T_ + t) * HW_ + n;
        for (int c = cg * 64; c < cg * 64 + 64; ++c) {
            const float v = p[c * TNH];
            s = fmaf(v, v, s);
        }
    }
    sm[cg][l] = s;
    __syncthreads();
    if (threadIdx.x < 64 && n < HW_) {
        const float tot = sm[0][l] + sm[1][l] + sm[2][l] + sm[3][l];
        invn[sl * HW_ + n] = 1.f / fmaxf(sqrtf(tot), 1e-12f);
    }
}

// ---------------- nxT: bf16 normalized features, transposed [sl][n][c] ----------------
__global__ __launch_bounds__(256) void k_nxT(
    const float* __restrict__ x1, const float* __restrict__ invn,
    ushort* __restrict__ nxT)
{
    __shared__ float xs[256][17];
    __shared__ float inv_s[16];
    const int sl = blockIdx.y, b = sl >> 3, t = sl & 7;
    const int n0 = blockIdx.x * 16;    // 49 blocks, 784 = 49*16 exact
    const int tid = threadIdx.x;
    {
        const int n_l = tid & 15;
        const int c0 = tid >> 4;       // 0..15
        const float* p = x1 + (b * C_ * T_ + c0 * T_ + t) * HW_ + n0 + n_l;
        #pragma unroll
        for (int i = 0; i < 16; ++i)
            xs[c0 + 16 * i][n_l] = p[(size_t)16 * i * TNH];
        if (tid < 16) inv_s[tid] = invn[sl * HW_ + n0 + tid];
    }
    __syncthreads();
    const int n_l = tid >> 4;
    const int cq = tid & 15;
    const float inv = inv_s[n_l];
    union { ushort u[16]; uint4 q[2]; } o;
    #pragma unroll
    for (int i = 0; i < 16; ++i)
        o.u[i] = f2bf(xs[cq * 16 + i][n_l] * inv);
    uint4* dst = (uint4*)(nxT + ((size_t)(sl * HW_ + n0 + n_l)) * 256 + cq * 16);
    dst[0] = o.q[0];
    dst[1] = o.q[1];
}

// ---------------- affinity row sum-exp via MFMA ----------------
// sumexp[s,sl,n] = sum_m exp(<nx[:,n], nx_sh[:,m]> / TEMP)
__global__ __launch_bounds__(256) void k_affinity_mfma(
    const ushort* __restrict__ nxT, float* __restrict__ sumexp)
{
    const int sl = blockIdx.y;           // 32
    const int s  = blockIdx.z;           // 3 shifts: 0=prev,1=next,2=id
    const int b = sl >> 3, t = sl & 7;
    const int t2 = (s == 0) ? (t > 0 ? t - 1 : 0) : (s == 1) ? (t < 7 ? t + 1 : 7) : t;
    const int sl2 = b * 8 + t2;
    const int wid = threadIdx.x >> 6;
    const int lane = threadIdx.x & 63;
    const int rt = blockIdx.x * 4 + wid; // row tile 0..48
    if (rt >= 49) return;
    const int n0 = rt * 16;
    const int r  = lane & 15;
    const int kg = lane >> 4;            // 0..3
    // A fragments: rows n0+r, k = kk*32 + kg*8 + [0..7]  (8 frags resident)
    const short* Abase = (const short*)nxT + ((size_t)sl * HW_ + n0 + r) * 256 + kg * 8;
    bf16x8 a[8];
    #pragma unroll
    for (int kk = 0; kk < 8; ++kk)
        a[kk] = *(const bf16x8*)(Abase + kk * 32);
    const short* Bbase = (const short*)nxT + (size_t)sl2 * HW_ * 256 + r * 256 + kg * 8;
    float re[4] = {0.f, 0.f, 0.f, 0.f};
    for (int mt = 0; mt < 49; ++mt) {
        f32x4 acc = {0.f, 0.f, 0.f, 0.f};
        const short* Bp = Bbase + (size_t)mt * 16 * 256;
        #pragma unroll
        for (int kk = 0; kk < 8; ++kk) {
            bf16x8 bfr = *(const bf16x8*)(Bp + kk * 32);
            acc = __builtin_amdgcn_mfma_f32_16x16x32_bf16(a[kk], bfr, acc, 0, 0, 0);
        }
        #pragma unroll
        for (int j = 0; j < 4; ++j)
            re[j] += __expf(acc[j] * TEMP_INV);
    }
    // D layout: col(m) = lane&15, row(n) = kg*4 + j.  Sum over m: reduce 16-lane group.
    #pragma unroll
    for (int j = 0; j < 4; ++j) {
        float v = re[j];
        v += __shfl_xor(v, 1);
        v += __shfl_xor(v, 2);
        v += __shfl_xor(v, 4);
        v += __shfl_xor(v, 8);
        re[j] = v;
    }
    if ((lane & 15) == 0) {
        #pragma unroll
        for (int j = 0; j < 4; ++j)
            sumexp[(s * BT_ + sl) * HW_ + n0 + kg * 4 + j] = re[j];
    }
}

// ---------------- diagonal similarity + diag_sm = exp(diag)/sumexp ----------------
__global__ __launch_bounds__(256) void k_diagsm(
    const float* __restrict__ x1, const float* __restrict__ invn,
    const float* __restrict__ sumexp, float* __restrict__ dsm)
{
    __shared__ float sm[3][4][64];
    const int sl = blockIdx.y, b = sl >> 3, t = sl & 7;
    const int l = threadIdx.x & 63;
    const int cg = threadIdx.x >> 6;
    const int n = blockIdx.x * 64 + l;
    const int tp = t > 0 ? t - 1 : 0;
    const int tn = t < 7 ? t + 1 : 7;
    float sp = 0.f, sn2 = 0.f, si = 0.f;
    if (n < HW_) {
        const float* p0 = x1 + (b * C_ * T_ + t) * HW_ + n;
        const float* pp = x1 + (b * C_ * T_ + tp) * HW_ + n;
        const float* pn = x1 + (b * C_ * T_ + tn) * HW_ + n;
        for (int c = cg * 64; c < cg * 64 + 64; ++c) {
            const float v = p0[c * TNH];
            sp  = fmaf(v, pp[c * TNH], sp);
            sn2 = fmaf(v, pn[c * TNH], sn2);
            si  = fmaf(v, v, si);
        }
    }
    sm[0][cg][l] = sp; sm[1][cg][l] = sn2; sm[2][cg][l] = si;
    __syncthreads();
    if (threadIdx.x < 64 && n < HW_) {
        const float d0 = sm[0][0][l] + sm[0][1][l] + sm[0][2][l] + sm[0][3][l];
        const float d1 = sm[1][0][l] + sm[1][1][l] + sm[1][2][l] + sm[1][3][l];
        const float d2 = sm[2][0][l] + sm[2][1][l] + sm[2][2][l] + sm[2][3][l];
        const float it  = invn[sl * HW_ + n];
        const float ip  = invn[(b * T_ + tp) * HW_ + n];
        const float in2 = invn[(b * T_ + tn) * HW_ + n];
        dsm[(0 * BT_ + sl) * HW_ + n] = __expf(d0 * it * ip  * TEMP_INV) / sumexp[(0 * BT_ + sl) * HW_ + n];
        dsm[(1 * BT_ + sl) * HW_ + n] = __expf(d1 * it * in2 * TEMP_INV) / sumexp[(1 * BT_ + sl) * HW_ + n];
        dsm[(2 * BT_ + sl) * HW_ + n] = __expf(d2 * it * it  * TEMP_INV) / sumexp[(2 * BT_ + sl) * HW_ + n];
    }
}

// ---------------- feats blend ----------------
__global__ __launch_bounds__(256) void k_feats(
    const float* __restrict__ x1, const float* __restrict__ dsm,
    float* __restrict__ feats)
{
    const int bct = blockIdx.x;
    const int t = bct & 7;
    const int c = (bct >> 3) & 255;
    const int b = bct >> 11;
    const int tp = t > 0 ? t - 1 : 0;
    const int tn = t < 7 ? t + 1 : 7;
    const int base = (b * C_ + c) * TNH;
    const float* dp = dsm + (0 * BT_ + b * T_ + t) * HW_;
    const float* dn = dsm + (1 * BT_ + b * T_ + t) * HW_;
    const float* di = dsm + (2 * BT_ + b * T_ + t) * HW_;
    const float* xp = x1 + base + tp * HW_;
    const float* xn = x1 + base + tn * HW_;
    const float* xi = x1 + base + t * HW_;
    float* fo = feats + base + t * HW_;
    for (int n = threadIdx.x; n < HW_; n += 256) {
        fo[n] = (dp[n] * xp[n] + dn[n] * xn[n] + di[n] * xi[n]) * (1.f / 3.f);
    }
}

// ---------------- depthwise 3D conv, 3 dilations fused ----------------
// One block per (b,r). Spatially zero-padded LDS [8][34*34]; each thread owns
// one pixel and accumulates all 8 t-outputs in registers (t-clip folds at
// compile time -> zero branches in the 1404-FMA unrolled body).
__global__ __launch_bounds__(768) void k_dwconv(
    const float* __restrict__ xx, const float* __restrict__ Wsa1,
    const float* __restrict__ Wsa2, const float* __restrict__ Wsa3,
    float* __restrict__ agg)
{
    __shared__ float xp[8 * 1156];   // [t][(h+3)*34 + (w+3)], 36992 B
    __shared__ float wl[3][81];
    const int br = blockIdx.x;       // b*RC + r
    const int r = br & 63;
    const int tid = threadIdx.x;
    const int base = br * TNH;
    // zero-fill (borders matter; bulk overwritten below)
    for (int i = tid; i < 8 * 1156; i += 768) xp[i] = 0.f;
    if (tid < 243) {
        const int s = tid / 81, k = tid % 81;
        const float* Wp = (s == 0) ? Wsa1 : (s == 1) ? Wsa2 : Wsa3;
        wl[s][k] = Wp[r * 81 + k] * (1.f / 3.f);
    }
    __syncthreads();
    for (int i = tid; i < TNH; i += 768) {
        const int t = i / HW_, p = i - t * HW_;
        const int h = p / 28, w = p - h * 28;
        xp[t * 1156 + (h + 3) * 34 + (w + 3)] = xx[base + i];
    }
    __syncthreads();
    for (int p = tid; p < HW_; p += 768) {
        const int h = p / 28, w = p - h * 28;
        const float* cen = &xp[(h + 3) * 34 + (w + 3)];
        float acc[8] = {0.f, 0.f, 0.f, 0.f, 0.f, 0.f, 0.f, 0.f};
        #pragma unroll
        for (int s = 0; s < 3; ++s) {
            const int d = s + 1;
            #pragma unroll
            for (int kh = 0; kh < 3; ++kh) {
                #pragma unroll
                for (int kw = 0; kw < 3; ++kw) {
                    const int off = (kh - 1) * d * 34 + (kw - 1) * d;
                    float wr[9];
                    #pragma unroll
                    for (int kt = 0; kt < 9; ++kt)
                        wr[kt] = wl[s][kt * 9 + kh * 3 + kw];
                    #pragma unroll
                    for (int ts = 0; ts < 8; ++ts) {
                        const float v = cen[ts * 1156 + off];
                        #pragma unroll
                        for (int kt = 0; kt < 9; ++kt) {
                            const int t = ts + 4 - kt;   // output t receiving this tap
                            if (t >= 0 && t < 8)
                                acc[t] = fmaf(v, wr[kt], acc[t]);
                        }
                    }
                }
            }
        }
        #pragma unroll
        for (int t = 0; t < 8; ++t)
            agg[base + t * HW_ + p] = acc[t];
    }
}

// ---------------- BN stats per channel ----------------
__global__ __launch_bounds__(256) void k_bnstats(
    const float* __restrict__ y, const float* __restrict__ gamma,
    const float* __restrict__ beta, float* __restrict__ stats)
{
    __shared__ float sm1[256], sm2[256];
    const int c = blockIdx.x;
    float s1 = 0.f, s2 = 0.f;
    for (int b = 0; b < B_; ++b) {
        const float* p = y + (b * C_ + c) * TNH;
        for (int i = threadIdx.x; i < TNH; i += 256) {
            const float v = p[i];
            s1 += v; s2 = fmaf(v, v, s2);
        }
    }
    sm1[threadIdx.x] = s1; sm2[threadIdx.x] = s2;
    __syncthreads();
    for (int off = 128; off > 0; off >>= 1) {
        if (threadIdx.x < off) {
            sm1[threadIdx.x] += sm1[threadIdx.x + off];
            sm2[threadIdx.x] += sm2[threadIdx.x + off];
        }
        __syncthreads();
    }
    if (threadIdx.x == 0) {
        const float M = (float)(B_ * TNH);
        const float mean = sm1[0] / M;
        const float var = sm2[0] / M - mean * mean;
        const float sc = gamma[c] * rsqrtf(var + 1e-5f);
        stats[c] = sc;
        stats[C_ + c] = beta[c] - mean * sc;
    }
}

// ---------------- BN apply + relu ----------------
__global__ __launch_bounds__(256) void k_bnapply(
    const float* __restrict__ y, const float* __restrict__ stats,
    float* __restrict__ out)
{
    const int total4 = B_ * C_ * TNH / 4;
    for (int i4 = blockIdx.x * 256 + threadIdx.x; i4 < total4; i4 += gridDim.x * 256) {
        float4 v = ((const float4*)y)[i4];
        const int c = (i4 / (TNH / 4)) & 255;
        const float sc = stats[c], bi = stats[C_ + c];
        v.x = fmaxf(fmaf(v.x, sc, bi), 0.f);
        v.y = fmaxf(fmaf(v.y, sc, bi), 0.f);
        v.z = fmaxf(fmaf(v.z, sc, bi), 0.f);
        v.w = fmaxf(fmaf(v.w, sc, bi), 0.f);
        ((float4*)out)[i4] = v;
    }
}

extern "C" void kernel_launch(void* const* d_in, const int* in_sizes, int n_in,
                              void* d_out, int out_size, void* d_ws, size_t ws_size,
                              hipStream_t stream) {
    (void)in_sizes; (void)n_in; (void)out_size; (void)ws_size;
    const float* x      = (const float*)d_in[0];
    const float* W_dc2  = (const float*)d_in[1];
    const float* W_up2  = (const float*)d_in[2];
    const float* W_dc   = (const float*)d_in[3];
    const float* Wsa1   = (const float*)d_in[4];
    const float* Wsa2   = (const float*)d_in[5];
    const float* Wsa3   = (const float*)d_in[6];
    const float* W_back = (const float*)d_in[7];
    const float* gamma  = (const float*)d_in[8];
    const float* beta   = (const float*)d_in[9];
    float* out = (float*)d_out;
    float* ws  = (float*)d_ws;

    const size_t NE = (size_t)B_ * C_ * TNH;       // 6,422,528
    float* x1     = ws;                            // x1, later fs
    float* buf2   = ws + NE;                       // nxT (bf16 alias), then feats, then y
    float* xx     = ws + 2 * NE;                   // 1,605,632
    float* agg    = xx + (size_t)B_ * RC_ * TNH;
    float* invn   = agg + (size_t)B_ * RC_ * TNH;  // 25,088
    float* sumexp = invn + (size_t)BT_ * HW_;      // 3*25,088
    float* dsm    = sumexp + 3 * (size_t)BT_ * HW_;
    float* stats  = dsm + 3 * (size_t)BT_ * HW_;   // 512
    ushort* nxT   = (ushort*)buf2;                 // 12.8 MB bf16, dead after k_affinity_mfma

    // 1. x1 = W_dc2 @ x
    k_conv1x1<0><<<dim3(4 * 13, 32), 256, 0, stream>>>(W_dc2, x, x1, nullptr, 256, 256, 4);
    // 2. invnorm
    k_invnorm<<<dim3(13, 32), 256, 0, stream>>>(x1, invn);
    // 3. nxT = bf16(x1 * invn), transposed to [sl][n][c]
    k_nxT<<<dim3(49, 32), 256, 0, stream>>>(x1, invn, nxT);
    // 4. affinity sum-exp for 3 shifts (MFMA)
    k_affinity_mfma<<<dim3(13, 32, 3), 256, 0, stream>>>(nxT, sumexp);
    // 5. diag_sm
    k_diagsm<<<dim3(13, 32), 256, 0, stream>>>(x1, invn, sumexp, dsm);
    // 6. feats blend -> buf2 (overwrites nxT, which is now dead)
    k_feats<<<8192, 256, 0, stream>>>(x1, dsm, buf2);
    // 7. xx = W_dc @ x1
    k_conv1x1<0><<<dim3(1 * 13, 32), 256, 0, stream>>>(W_dc, x1, xx, nullptr, 64, 256, 1);
    // 8. agg = mean of 3 dilated dwconvs (one block per (b,r), all t in regs)
    k_dwconv<<<256, 768, 0, stream>>>(xx, Wsa1, Wsa2, Wsa3, agg);
    // 9. fs = relu(W_back @ agg) * feats -> overwrite x1 buffer
    k_conv1x1<1><<<dim3(4 * 13, 32), 256, 0, stream>>>(W_back, agg, x1, buf2, 256, 64, 4);
    // 10. y = x + W_up2 @ fs -> buf2
    k_conv1x1<2><<<dim3(4 * 13, 32), 256, 0, stream>>>(W_up2, x1, buf2, x, 256, 256, 4);
    // 11. BN stats
    k_bnstats<<<256, 256, 0, stream>>>(buf2, gamma, beta, stats);
    // 12. BN apply + relu -> out
    k_bnapply<<<2048, 256, 0, stream>>>(buf2, stats, out);
}

// Round 4
// 433.852 us; speedup vs baseline: 3.2158x; 1.3982x over previous
//
#include <hip/hip_runtime.h>

#define B_ 4
#define C_ 256
#define T_ 8
#define HW_ 784
#define RC_ 64
#define TNH (T_*HW_)   // 6272
#define BT_ (B_*T_)    // 32
#define TEMP_INV 14.28571428571f  // 1/0.07

typedef __attribute__((ext_vector_type(8))) short bf16x8;
typedef __attribute__((ext_vector_type(4))) float f32x4;

__device__ __forceinline__ float4 ld4s(const float* p) { return *(const float4*)p; }

__device__ __forceinline__ ushort f2bf(float f) {
    uint x = __float_as_uint(f);
    uint r = (x + 0x7FFFu + ((x >> 16) & 1u)) >> 16;   // RNE
    return (ushort)r;
}

#define GL2LDS16(g, l) __builtin_amdgcn_global_load_lds( \
    (const __attribute__((address_space(1))) void*)(g), \
    (__attribute__((address_space(3))) void*)(l), 16, 0, 0)

// ---------------- conv1x1 GEMM: Y[b,o,t,n] = sum_c W[o,c] * X[b,c,t,n] ----------------
// MODE 0: plain.  MODE 1: Y = relu(acc) * aux.  MODE 2: Y = acc + aux.
template<int MODE>
__global__ __launch_bounds__(256) void k_conv1x1(
    const float* __restrict__ Wm, const float* __restrict__ X,
    float* __restrict__ Y, const float* __restrict__ aux,
    int M, int K, int mtiles)
{
    __shared__ float Ws[16][68];   // [c][o], padded
    __shared__ float Xs[16][64];   // [c][n]
    const int sl = blockIdx.y;
    const int b = sl >> 3, t = sl & 7;
    const int bx = blockIdx.x;
    const int mt = bx % mtiles;
    const int nt = bx / mtiles;
    const int o0 = mt * 64, n0 = nt * 64;
    const int tid = threadIdx.x;
    const int tx = tid & 15, ty = tid >> 4;
    const float* Xb = X + (b * K * T_ + t) * HW_;
    const int nl = tid & 63;
    const int cb = tid >> 6;
    const bool nok = (n0 + nl) < HW_;
    float acc[4][4] = {};
    for (int k0 = 0; k0 < K; k0 += 16) {
        __syncthreads();
        #pragma unroll
        for (int p = 0; p < 4; ++p) {
            int o = p * 16 + ty;
            Ws[tx][o] = Wm[(o0 + o) * K + k0 + tx];
        }
        #pragma unroll
        for (int p = 0; p < 4; ++p) {
            int c = p * 4 + cb;
            Xs[c][nl] = nok ? Xb[(k0 + c) * TNH + n0 + nl] : 0.f;
        }
        __syncthreads();
        #pragma unroll
        for (int kk = 0; kk < 16; ++kk) {
            float4 av = ld4s(&Ws[kk][ty * 4]);
            float4 bv = ld4s(&Xs[kk][tx * 4]);
            float a_[4] = {av.x, av.y, av.z, av.w};
            float b_[4] = {bv.x, bv.y, bv.z, bv.w};
            #pragma unroll
            for (int i = 0; i < 4; ++i)
                #pragma unroll
                for (int j = 0; j < 4; ++j)
                    acc[i][j] = fmaf(a_[i], b_[j], acc[i][j]);
        }
    }
    const int ybase = (b * M) * TNH + t * HW_;
    #pragma unroll
    for (int i = 0; i < 4; ++i) {
        const int o = o0 + ty * 4 + i;
        #pragma unroll
        for (int j = 0; j < 4; ++j) {
            const int n = n0 + tx * 4 + j;
            if (n < HW_) {
                const int idx = ybase + o * TNH + n;
                float v = acc[i][j];
                if (MODE == 1) v = fmaxf(v, 0.f) * aux[idx];
                else if (MODE == 2) v += aux[idx];
                Y[idx] = v;
            }
        }
    }
}

// ---------------- inverse norm over channels ----------------
__global__ __launch_bounds__(256) void k_invnorm(
    const float* __restrict__ x1, float* __restrict__ invn)
{
    __shared__ float sm[4][64];
    const int sl = blockIdx.y, b = sl >> 3, t = sl & 7;
    const int l = threadIdx.x & 63;
    const int cg = threadIdx.x >> 6;
    const int n = blockIdx.x * 64 + l;
    float s = 0.f;
    if (n < HW_) {
        const float* p = x1 + (b * C_ * T_ + t) * HW_ + n;
        for (int c = cg * 64; c < cg * 64 + 64; ++c) {
            const float v = p[c * TNH];
            s = fmaf(v, v, s);
        }
    }
    sm[cg][l] = s;
    __syncthreads();
    if (threadIdx.x < 64 && n < HW_) {
        const float tot = sm[0][l] + sm[1][l] + sm[2][l] + sm[3][l];
        invn[sl * HW_ + n] = 1.f / fmaxf(sqrtf(tot), 1e-12f);
    }
}

// ---------------- nxT: bf16 normalized features, transposed [sl][n][c] ----------------
__global__ __launch_bounds__(256) void k_nxT(
    const float* __restrict__ x1, const float* __restrict__ invn,
    ushort* __restrict__ nxT)
{
    __shared__ float xs[256][17];
    __shared__ float inv_s[16];
    const int sl = blockIdx.y, b = sl >> 3, t = sl & 7;
    const int n0 = blockIdx.x * 16;    // 49 blocks, 784 = 49*16 exact
    const int tid = threadIdx.x;
    {
        const int n_l = tid & 15;
        const int c0 = tid >> 4;       // 0..15
        const float* p = x1 + (b * C_ * T_ + c0 * T_ + t) * HW_ + n0 + n_l;
        #pragma unroll
        for (int i = 0; i < 16; ++i)
            xs[c0 + 16 * i][n_l] = p[(size_t)16 * i * TNH];
        if (tid < 16) inv_s[tid] = invn[sl * HW_ + n0 + tid];
    }
    __syncthreads();
    const int n_l = tid >> 4;
    const int cq = tid & 15;
    const float inv = inv_s[n_l];
    union { ushort u[16]; uint4 q[2]; } o;
    #pragma unroll
    for (int i = 0; i < 16; ++i)
        o.u[i] = f2bf(xs[cq * 16 + i][n_l] * inv);
    uint4* dst = (uint4*)(nxT + ((size_t)(sl * HW_ + n0 + n_l)) * 256 + cq * 16);
    dst[0] = o.q[0];
    dst[1] = o.q[1];
}

// ---------------- affinity row sum-exp via MFMA, LDS-staged double-buffered B ----------------
// sumexp[s,sl,n] = sum_m exp(<nx[:,n], nx_sh[:,m]> / TEMP)
// Block: 4 waves, each owns 2 row-tiles (32 rows); B chunk (16 m x 256 k bf16 = 8 KB)
// shared by all waves, staged via global_load_lds with XOR-swizzled source (T2/rule 21).
__global__ __launch_bounds__(256) void k_affinity_mfma(
    const ushort* __restrict__ nxT, float* __restrict__ sumexp)
{
    __shared__ __align__(16) ushort Bs[2][16 * 256];   // 2 x 8 KB
    const int sl = blockIdx.y;           // 32
    const int s  = blockIdx.z;           // 3 shifts: 0=prev,1=next,2=id
    const int b = sl >> 3, t = sl & 7;
    const int t2 = (s == 0) ? (t > 0 ? t - 1 : 0) : (s == 1) ? (t < 7 ? t + 1 : 7) : t;
    const int sl2 = b * 8 + t2;
    const int wid = threadIdx.x >> 6;
    const int lane = threadIdx.x & 63;
    const int r  = lane & 15;
    const int kg = lane >> 4;            // 0..3

    const int tile0_raw = blockIdx.x * 8 + wid * 2;   // 0..55 (49 valid)
    const int tile0 = min(tile0_raw, 48);
    const int tile1 = min(tile0_raw + 1, 48);

    // A fragments: 2 tiles x 8 kk, rows tile*16+r, k = kk*32 + kg*8 + [0..7]
    const short* Ab = (const short*)nxT + (size_t)sl * HW_ * 256 + kg * 8;
    bf16x8 a0[8], a1[8];
    #pragma unroll
    for (int kk = 0; kk < 8; ++kk) {
        a0[kk] = *(const bf16x8*)(Ab + (size_t)(tile0 * 16 + r) * 256 + kk * 32);
        a1[kk] = *(const bf16x8*)(Ab + (size_t)(tile1 * 16 + r) * 256 + kk * 32);
    }
    // pin A in registers (round-2's VGPR=28 showed the compiler re-sinking these loads)
    #pragma unroll
    for (int kk = 0; kk < 8; ++kk) {
        asm volatile("" : "+v"(a0[kk]));
        asm volatile("" : "+v"(a1[kk]));
    }

    const ushort* Bsrc = nxT + (size_t)sl2 * HW_ * 256;

    // stage chunk ch into Bs[buf]: 512 slots of 16 B; slot = m*32 + (j ^ (m&7))
    // LDS written linearly (base + lane*16); source pre-swizzled.
    #define STAGE_AFF(buf, ch) do {                                           \
        _Pragma("unroll")                                                     \
        for (int e = 0; e < 2; ++e) {                                         \
            const int slot = wid * 128 + e * 64 + lane;                       \
            const int m = slot >> 5;                                          \
            const int j = (slot & 31) ^ (m & 7);                              \
            const ushort* g = Bsrc + (size_t)((ch) * 16 + m) * 256 + j * 8;   \
            ushort* l = &Bs[buf][(size_t)(wid * 128 + e * 64) * 8];           \
            GL2LDS16(g, l);                                                   \
        }                                                                     \
    } while (0)

    float re0[4] = {0.f, 0.f, 0.f, 0.f};
    float re1[4] = {0.f, 0.f, 0.f, 0.f};

    STAGE_AFF(0, 0);
    __syncthreads();                      // drains vmcnt -> buf0 ready
    for (int ch = 0; ch < 49; ++ch) {
        const int cur = ch & 1;
        if (ch + 1 < 49) STAGE_AFF(cur ^ 1, ch + 1);
        f32x4 acc0 = {0.f, 0.f, 0.f, 0.f};
        f32x4 acc1 = {0.f, 0.f, 0.f, 0.f};
        #pragma unroll
        for (int kk = 0; kk < 8; ++kk) {
            const int gidx = (kk * 4 + kg) ^ (r & 7);
            bf16x8 bfr = *(const bf16x8*)&Bs[cur][(size_t)(r * 32 + gidx) * 8];
            acc0 = __builtin_amdgcn_mfma_f32_16x16x32_bf16(a0[kk], bfr, acc0, 0, 0, 0);
            acc1 = __builtin_amdgcn_mfma_f32_16x16x32_bf16(a1[kk], bfr, acc1, 0, 0, 0);
        }
        #pragma unroll
        for (int j = 0; j < 4; ++j) {
            re0[j] += __expf(acc0[j] * TEMP_INV);
            re1[j] += __expf(acc1[j] * TEMP_INV);
        }
        __syncthreads();                  // buf[cur^1] ready for next iter; buf[cur] safe to overwrite
    }

    // D layout: col(m) = lane&15, row(n) = kg*4 + j. Sum over m -> reduce 16-lane group.
    #pragma unroll
    for (int j = 0; j < 4; ++j) {
        float v0 = re0[j], v1 = re1[j];
        v0 += __shfl_xor(v0, 1); v1 += __shfl_xor(v1, 1);
        v0 += __shfl_xor(v0, 2); v1 += __shfl_xor(v1, 2);
        v0 += __shfl_xor(v0, 4); v1 += __shfl_xor(v1, 4);
        v0 += __shfl_xor(v0, 8); v1 += __shfl_xor(v1, 8);
        re0[j] = v0; re1[j] = v1;
    }
    float* dst = sumexp + (s * BT_ + sl) * HW_;
    if ((lane & 15) == 0) {
        if (tile0_raw < 49) {
            #pragma unroll
            for (int j = 0; j < 4; ++j)
                dst[tile0_raw * 16 + kg * 4 + j] = re0[j];
        }
        if (tile0_raw + 1 < 49) {
            #pragma unroll
            for (int j = 0; j < 4; ++j)
                dst[(tile0_raw + 1) * 16 + kg * 4 + j] = re1[j];
        }
    }
    #undef STAGE_AFF
}

// ---------------- diagonal similarity + diag_sm = exp(diag)/sumexp ----------------
__global__ __launch_bounds__(256) void k_diagsm(
    const float* __restrict__ x1, const float* __restrict__ invn,
    const float* __restrict__ sumexp, float* __restrict__ dsm)
{
    __shared__ float sm[3][4][64];
    const int sl = blockIdx.y, b = sl >> 3, t = sl & 7;
    const int l = threadIdx.x & 63;
    const int cg = threadIdx.x >> 6;
    const int n = blockIdx.x * 64 + l;
    const int tp = t > 0 ? t - 1 : 0;
    const int tn = t < 7 ? t + 1 : 7;
    float sp = 0.f, sn2 = 0.f, si = 0.f;
    if (n < HW_) {
        const float* p0 = x1 + (b * C_ * T_ + t) * HW_ + n;
        const float* pp = x1 + (b * C_ * T_ + tp) * HW_ + n;
        const float* pn = x1 + (b * C_ * T_ + tn) * HW_ + n;
        for (int c = cg * 64; c < cg * 64 + 64; ++c) {
            const float v = p0[c * TNH];
            sp  = fmaf(v, pp[c * TNH], sp);
            sn2 = fmaf(v, pn[c * TNH], sn2);
            si  = fmaf(v, v, si);
        }
    }
    sm[0][cg][l] = sp; sm[1][cg][l] = sn2; sm[2][cg][l] = si;
    __syncthreads();
    if (threadIdx.x < 64 && n < HW_) {
        const float d0 = sm[0][0][l] + sm[0][1][l] + sm[0][2][l] + sm[0][3][l];
        const float d1 = sm[1][0][l] + sm[1][1][l] + sm[1][2][l] + sm[1][3][l];
        const float d2 = sm[2][0][l] + sm[2][1][l] + sm[2][2][l] + sm[2][3][l];
        const float it  = invn[sl * HW_ + n];
        const float ip  = invn[(b * T_ + tp) * HW_ + n];
        const float in2 = invn[(b * T_ + tn) * HW_ + n];
        dsm[(0 * BT_ + sl) * HW_ + n] = __expf(d0 * it * ip  * TEMP_INV) / sumexp[(0 * BT_ + sl) * HW_ + n];
        dsm[(1 * BT_ + sl) * HW_ + n] = __expf(d1 * it * in2 * TEMP_INV) / sumexp[(1 * BT_ + sl) * HW_ + n];
        dsm[(2 * BT_ + sl) * HW_ + n] = __expf(d2 * it * it  * TEMP_INV) / sumexp[(2 * BT_ + sl) * HW_ + n];
    }
}

// ---------------- feats blend ----------------
__global__ __launch_bounds__(256) void k_feats(
    const float* __restrict__ x1, const float* __restrict__ dsm,
    float* __restrict__ feats)
{
    const int bct = blockIdx.x;
    const int t = bct & 7;
    const int c = (bct >> 3) & 255;
    const int b = bct >> 11;
    const int tp = t > 0 ? t - 1 : 0;
    const int tn = t < 7 ? t + 1 : 7;
    const int base = (b * C_ + c) * TNH;
    const float* dp = dsm + (0 * BT_ + b * T_ + t) * HW_;
    const float* dn = dsm + (1 * BT_ + b * T_ + t) * HW_;
    const float* di = dsm + (2 * BT_ + b * T_ + t) * HW_;
    const float* xp = x1 + base + tp * HW_;
    const float* xn = x1 + base + tn * HW_;
    const float* xi = x1 + base + t * HW_;
    float* fo = feats + base + t * HW_;
    for (int n = threadIdx.x; n < HW_; n += 256) {
        fo[n] = (dp[n] * xp[n] + dn[n] * xn[n] + di[n] * xi[n]) * (1.f / 3.f);
    }
}

// ---------------- depthwise 3D conv, 3 dilations fused ----------------
__global__ __launch_bounds__(768) void k_dwconv(
    const float* __restrict__ xx, const float* __restrict__ Wsa1,
    const float* __restrict__ Wsa2, const float* __restrict__ Wsa3,
    float* __restrict__ agg)
{
    __shared__ float xp[8 * 1156];   // [t][(h+3)*34 + (w+3)], 36992 B
    __shared__ float wl[3][81];
    const int br = blockIdx.x;       // b*RC + r
    const int r = br & 63;
    const int tid = threadIdx.x;
    const int base = br * TNH;
    for (int i = tid; i < 8 * 1156; i += 768) xp[i] = 0.f;
    if (tid < 243) {
        const int s = tid / 81, k = tid % 81;
        const float* Wp = (s == 0) ? Wsa1 : (s == 1) ? Wsa2 : Wsa3;
        wl[s][k] = Wp[r * 81 + k] * (1.f / 3.f);
    }
    __syncthreads();
    for (int i = tid; i < TNH; i += 768) {
        const int t = i / HW_, p = i - t * HW_;
        const int h = p / 28, w = p - h * 28;
        xp[t * 1156 + (h + 3) * 34 + (w + 3)] = xx[base + i];
    }
    __syncthreads();
    for (int p = tid; p < HW_; p += 768) {
        const int h = p / 28, w = p - h * 28;
        const float* cen = &xp[(h + 3) * 34 + (w + 3)];
        float acc[8] = {0.f, 0.f, 0.f, 0.f, 0.f, 0.f, 0.f, 0.f};
        #pragma unroll
        for (int s = 0; s < 3; ++s) {
            const int d = s + 1;
            #pragma unroll
            for (int kh = 0; kh < 3; ++kh) {
                #pragma unroll
                for (int kw = 0; kw < 3; ++kw) {
                    const int off = (kh - 1) * d * 34 + (kw - 1) * d;
                    float wr[9];
                    #pragma unroll
                    for (int kt = 0; kt < 9; ++kt)
                        wr[kt] = wl[s][kt * 9 + kh * 3 + kw];
                    #pragma unroll
                    for (int ts = 0; ts < 8; ++ts) {
                        const float v = cen[ts * 1156 + off];
                        #pragma unroll
                        for (int kt = 0; kt < 9; ++kt) {
                            const int t = ts + 4 - kt;
                            if (t >= 0 && t < 8)
                                acc[t] = fmaf(v, wr[kt], acc[t]);
                        }
                    }
                }
            }
        }
        #pragma unroll
        for (int t = 0; t < 8; ++t)
            agg[base + t * HW_ + p] = acc[t];
    }
}

// ---------------- BN stats per channel ----------------
__global__ __launch_bounds__(256) void k_bnstats(
    const float* __restrict__ y, const float* __restrict__ gamma,
    const float* __restrict__ beta, float* __restrict__ stats)
{
    __shared__ float sm1[256], sm2[256];
    const int c = blockIdx.x;
    float s1 = 0.f, s2 = 0.f;
    for (int b = 0; b < B_; ++b) {
        const float* p = y + (b * C_ + c) * TNH;
        for (int i = threadIdx.x; i < TNH; i += 256) {
            const float v = p[i];
            s1 += v; s2 = fmaf(v, v, s2);
        }
    }
    sm1[threadIdx.x] = s1; sm2[threadIdx.x] = s2;
    __syncthreads();
    for (int off = 128; off > 0; off >>= 1) {
        if (threadIdx.x < off) {
            sm1[threadIdx.x] += sm1[threadIdx.x + off];
            sm2[threadIdx.x] += sm2[threadIdx.x + off];
        }
        __syncthreads();
    }
    if (threadIdx.x == 0) {
        const float M = (float)(B_ * TNH);
        const float mean = sm1[0] / M;
        const float var = sm2[0] / M - mean * mean;
        const float sc = gamma[c] * rsqrtf(var + 1e-5f);
        stats[c] = sc;
        stats[C_ + c] = beta[c] - mean * sc;
    }
}

// ---------------- BN apply + relu ----------------
__global__ __launch_bounds__(256) void k_bnapply(
    const float* __restrict__ y, const float* __restrict__ stats,
    float* __restrict__ out)
{
    const int total4 = B_ * C_ * TNH / 4;
    for (int i4 = blockIdx.x * 256 + threadIdx.x; i4 < total4; i4 += gridDim.x * 256) {
        float4 v = ((const float4*)y)[i4];
        const int c = (i4 / (TNH / 4)) & 255;
        const float sc = stats[c], bi = stats[C_ + c];
        v.x = fmaxf(fmaf(v.x, sc, bi), 0.f);
        v.y = fmaxf(fmaf(v.y, sc, bi), 0.f);
        v.z = fmaxf(fmaf(v.z, sc, bi), 0.f);
        v.w = fmaxf(fmaf(v.w, sc, bi), 0.f);
        ((float4*)out)[i4] = v;
    }
}

extern "C" void kernel_launch(void* const* d_in, const int* in_sizes, int n_in,
                              void* d_out, int out_size, void* d_ws, size_t ws_size,
                              hipStream_t stream) {
    (void)in_sizes; (void)n_in; (void)out_size; (void)ws_size;
    const float* x      = (const float*)d_in[0];
    const float* W_dc2  = (const float*)d_in[1];
    const float* W_up2  = (const float*)d_in[2];
    const float* W_dc   = (const float*)d_in[3];
    const float* Wsa1   = (const float*)d_in[4];
    const float* Wsa2   = (const float*)d_in[5];
    const float* Wsa3   = (const float*)d_in[6];
    const float* W_back = (const float*)d_in[7];
    const float* gamma  = (const float*)d_in[8];
    const float* beta   = (const float*)d_in[9];
    float* out = (float*)d_out;
    float* ws  = (float*)d_ws;

    const size_t NE = (size_t)B_ * C_ * TNH;       // 6,422,528
    float* x1     = ws;                            // x1, later fs
    float* buf2   = ws + NE;                       // nxT (bf16 alias), then feats, then y
    float* xx     = ws + 2 * NE;                   // 1,605,632
    float* agg    = xx + (size_t)B_ * RC_ * TNH;
    float* invn   = agg + (size_t)B_ * RC_ * TNH;  // 25,088
    float* sumexp = invn + (size_t)BT_ * HW_;      // 3*25,088
    float* dsm    = sumexp + 3 * (size_t)BT_ * HW_;
    float* stats  = dsm + 3 * (size_t)BT_ * HW_;   // 512
    ushort* nxT   = (ushort*)buf2;                 // 12.8 MB bf16, dead after k_affinity_mfma

    // 1. x1 = W_dc2 @ x
    k_conv1x1<0><<<dim3(4 * 13, 32), 256, 0, stream>>>(W_dc2, x, x1, nullptr, 256, 256, 4);
    // 2. invnorm
    k_invnorm<<<dim3(13, 32), 256, 0, stream>>>(x1, invn);
    // 3. nxT = bf16(x1 * invn), transposed to [sl][n][c]
    k_nxT<<<dim3(49, 32), 256, 0, stream>>>(x1, invn, nxT);
    // 4. affinity sum-exp for 3 shifts (MFMA, LDS double-buffered)
    k_affinity_mfma<<<dim3(7, 32, 3), 256, 0, stream>>>(nxT, sumexp);
    // 5. diag_sm
    k_diagsm<<<dim3(13, 32), 256, 0, stream>>>(x1, invn, sumexp, dsm);
    // 6. feats blend -> buf2 (overwrites nxT, which is now dead)
    k_feats<<<8192, 256, 0, stream>>>(x1, dsm, buf2);
    // 7. xx = W_dc @ x1
    k_conv1x1<0><<<dim3(1 * 13, 32), 256, 0, stream>>>(W_dc, x1, xx, nullptr, 64, 256, 1);
    // 8. agg = mean of 3 dilated dwconvs (one block per (b,r), all t in regs)
    k_dwconv<<<256, 768, 0, stream>>>(xx, Wsa1, Wsa2, Wsa3, agg);
    // 9. fs = relu(W_back @ agg) * feats -> overwrite x1 buffer
    k_conv1x1<1><<<dim3(4 * 13, 32), 256, 0, stream>>>(W_back, agg, x1, buf2, 256, 64, 4);
    // 10. y = x + W_up2 @ fs -> buf2
    k_conv1x1<2><<<dim3(4 * 13, 32), 256, 0, stream>>>(W_up2, x1, buf2, x, 256, 256, 4);
    // 11. BN stats
    k_bnstats<<<256, 256, 0, stream>>>(buf2, gamma, beta, stats);
    // 12. BN apply + relu -> out
    k_bnapply<<<2048, 256, 0, stream>>>(buf2, stats, out);
}

// Round 5
// 323.378 us; speedup vs baseline: 4.3144x; 1.3416x over previous
//
#include <hip/hip_runtime.h>

#define B_ 4
#define C_ 256
#define T_ 8
#define HW_ 784
#define RC_ 64
#define TNH (T_*HW_)   // 6272
#define BT_ (B_*T_)    // 32
#define TEMP_INV 14.28571428571f  // 1/0.07

typedef __attribute__((ext_vector_type(8))) short bf16x8;
typedef __attribute__((ext_vector_type(4))) float f32x4;

__device__ __forceinline__ ushort f2bf(float f) {
    uint x = __float_as_uint(f);
    uint r = (x + 0x7FFFu + ((x >> 16) & 1u)) >> 16;   // RNE
    return (ushort)r;
}

#define GL2LDS16(g, l) __builtin_amdgcn_global_load_lds( \
    (const __attribute__((address_space(1))) void*)(g), \
    (__attribute__((address_space(3))) void*)(l), 16, 0, 0)

// ---------------- weight fp32 -> bf16 (all four, packed into one buffer) ----------------
// layout (ushort idx): [0,65536) W_dc2 | [65536,131072) W_up2 | [131072,147456) W_dc | [147456,163840) W_back
__global__ __launch_bounds__(256) void k_wcvt(
    const float* __restrict__ w_dc2, const float* __restrict__ w_up2,
    const float* __restrict__ w_dc, const float* __restrict__ w_back,
    ushort* __restrict__ dst)
{
    const int idx = blockIdx.x * 256 + threadIdx.x;
    if (idx >= 163840) return;
    float v;
    if (idx < 65536)       v = w_dc2[idx];
    else if (idx < 131072) v = w_up2[idx - 65536];
    else if (idx < 147456) v = w_dc[idx - 131072];
    else                   v = w_back[idx - 147456];
    dst[idx] = f2bf(v);
}

// ---------------- transpose fp32 [b][256][t][n] -> bf16 [sl][n][256] ----------------
__global__ __launch_bounds__(256) void k_xpose(
    const float* __restrict__ X, ushort* __restrict__ XT)
{
    __shared__ float xs[256][17];
    const int sl = blockIdx.y, b = sl >> 3, t = sl & 7;
    const int n0 = blockIdx.x * 16;
    const int tid = threadIdx.x;
    {
        const int n_l = tid & 15;
        const int c0 = tid >> 4;
        const float* p = X + (b * C_ * T_ + c0 * T_ + t) * HW_ + n0 + n_l;
        #pragma unroll
        for (int i = 0; i < 16; ++i)
            xs[c0 + 16 * i][n_l] = p[(size_t)16 * i * TNH];
    }
    __syncthreads();
    const int n_l = tid >> 4;
    const int cq = tid & 15;
    union { ushort u[16]; uint4 q[2]; } o;
    #pragma unroll
    for (int i = 0; i < 16; ++i)
        o.u[i] = f2bf(xs[cq * 16 + i][n_l]);
    uint4* dst = (uint4*)(XT + ((size_t)(sl * HW_ + n0 + n_l)) * 256 + cq * 16);
    dst[0] = o.q[0];
    dst[1] = o.q[1];
}

// ---------------- transpose fp32 agg [b][64][t][n] -> bf16 [sl][n][64] ----------------
__global__ __launch_bounds__(256) void k_xpose64(
    const float* __restrict__ A, ushort* __restrict__ AT)
{
    __shared__ float xs[64][17];
    const int sl = blockIdx.y, b = sl >> 3, t = sl & 7;
    const int n0 = blockIdx.x * 16;
    const int tid = threadIdx.x;
    {
        const int n_l = tid & 15;
        const int c0 = tid >> 4;
        #pragma unroll
        for (int i = 0; i < 4; ++i)
            xs[c0 + 16 * i][n_l] = A[((size_t)(b * RC_ + c0 + 16 * i) * T_ + t) * HW_ + n0 + n_l];
    }
    __syncthreads();
    const int n_l = tid >> 4;
    const int cq = tid & 15;
    union { ushort u[4]; uint2 q; } o;
    #pragma unroll
    for (int i = 0; i < 4; ++i)
        o.u[i] = f2bf(xs[cq * 4 + i][n_l]);
    *(uint2*)(AT + ((size_t)(sl * HW_ + n0 + n_l)) * 64 + cq * 4) = o.q;
}

// ---------------- generic MFMA conv1x1, channel-major fp32 output ----------------
// Y[b][o][t][n] = sum_k W[o,k] * XT[sl][n][k]   (o = ch*16 + lane&15, n-rows from acc)
// MODE 0: plain.  MODE 1: *= aux[sl*HW+n] (norm).  MODE 2: += aux (x residual, C=256).
template<int MCH, int KK, int MODE>
__global__ __launch_bounds__(256) void k_gemm_cm(
    const ushort* __restrict__ Wsrc, const ushort* __restrict__ XT,
    float* __restrict__ Y, const float* __restrict__ aux)
{
    constexpr int KD = KK * 32;
    constexpr int GPR = KD / 8;      // 16B granules per weight row
    constexpr int M = MCH * 16;
    __shared__ __align__(16) ushort Bs[2][16 * KD];
    const int sl = blockIdx.y, b = sl >> 3, t = sl & 7;
    const int wid = threadIdx.x >> 6, lane = threadIdx.x & 63;
    const int r = lane & 15, kg = lane >> 4;
    const int tile0_raw = blockIdx.x * 8 + wid * 2;
    const int tile0 = min(tile0_raw, 48), tile1 = min(tile0_raw + 1, 48);

    const short* Ab = (const short*)XT + (size_t)sl * HW_ * KD + kg * 8;
    bf16x8 a0[KK], a1[KK];
    #pragma unroll
    for (int kk = 0; kk < KK; ++kk) {
        a0[kk] = *(const bf16x8*)(Ab + (size_t)(tile0 * 16 + r) * KD + kk * 32);
        a1[kk] = *(const bf16x8*)(Ab + (size_t)(tile1 * 16 + r) * KD + kk * 32);
    }
    #pragma unroll
    for (int kk = 0; kk < KK; ++kk) {
        asm volatile("" : "+v"(a0[kk]));
        asm volatile("" : "+v"(a1[kk]));
    }

    f32x4 nrm0, nrm1;
    if (MODE == 1) {
        nrm0 = *(const f32x4*)&aux[sl * HW_ + tile0 * 16 + kg * 4];
        nrm1 = *(const f32x4*)&aux[sl * HW_ + tile1 * 16 + kg * 4];
    }

    #define STAGE_W(buf, ch) do {                                              \
        if (KK == 8) {                                                         \
            _Pragma("unroll")                                                  \
            for (int e = 0; e < 2; ++e) {                                      \
                const int slot = wid * 128 + e * 64 + lane;                    \
                const int m = slot >> 5;                                       \
                const int j = (slot & 31) ^ (m & 7);                           \
                const ushort* g = Wsrc + (size_t)((ch) * 16 + m) * KD + j * 8; \
                ushort* l = &Bs[buf][(size_t)(wid * 128 + e * 64) * 8];        \
                GL2LDS16(g, l);                                                \
            }                                                                  \
        } else {                                                               \
            if (wid < 2) {                                                     \
                const int slot = wid * 64 + lane;                              \
                const int m = slot >> 3;                                       \
                const int j = (slot & 7) ^ (m & 7);                            \
                const ushort* g = Wsrc + (size_t)((ch) * 16 + m) * KD + j * 8; \
                ushort* l = &Bs[buf][(size_t)(wid * 64) * 8];                  \
                GL2LDS16(g, l);                                                \
            }                                                                  \
        }                                                                      \
    } while (0)

    STAGE_W(0, 0);
    __syncthreads();
    for (int ch = 0; ch < MCH; ++ch) {
        const int cur = ch & 1;
        if (ch + 1 < MCH) STAGE_W(cur ^ 1, ch + 1);
        f32x4 acc0 = {0.f, 0.f, 0.f, 0.f};
        f32x4 acc1 = {0.f, 0.f, 0.f, 0.f};
        #pragma unroll
        for (int kk = 0; kk < KK; ++kk) {
            const int gidx = (kk * 4 + kg) ^ (r & 7);
            bf16x8 bfr = *(const bf16x8*)&Bs[cur][(size_t)(r * GPR + gidx) * 8];
            acc0 = __builtin_amdgcn_mfma_f32_16x16x32_bf16(a0[kk], bfr, acc0, 0, 0, 0);
            acc1 = __builtin_amdgcn_mfma_f32_16x16x32_bf16(a1[kk], bfr, acc1, 0, 0, 0);
        }
        const int o = ch * 16 + r;
        const size_t ybase = ((size_t)(b * M + o) * T_ + t) * HW_;
        if (tile0_raw < 49) {
            const int n0 = tile0_raw * 16 + kg * 4;
            f32x4 v = acc0;
            if (MODE == 1) v *= nrm0;
            if (MODE == 2) v += *(const f32x4*)&aux[((size_t)(b * C_ + o) * T_ + t) * HW_ + n0];
            *(f32x4*)&Y[ybase + n0] = v;
        }
        if (tile0_raw + 1 < 49) {
            const int n0 = (tile0_raw + 1) * 16 + kg * 4;
            f32x4 v = acc1;
            if (MODE == 1) v *= nrm1;
            if (MODE == 2) v += *(const f32x4*)&aux[((size_t)(b * C_ + o) * T_ + t) * HW_ + n0];
            *(f32x4*)&Y[ybase + n0] = v;
        }
        __syncthreads();
    }
    #undef STAGE_W
}

// ---------------- score GEMM (K=64) with fused relu*feats epilogue -> fsT bf16 [sl][n][256] ----------------
__global__ __launch_bounds__(256) void k_gemm_fs(
    const ushort* __restrict__ Wsrc, const ushort* __restrict__ aggT,
    const float* __restrict__ x1, const float* __restrict__ dsm,
    ushort* __restrict__ fsT)
{
    __shared__ __align__(16) ushort Bs[2][16 * 64];
    const int sl = blockIdx.y, b = sl >> 3, t = sl & 7;
    const int tp = t > 0 ? t - 1 : 0;
    const int tn = t < 7 ? t + 1 : 7;
    const int wid = threadIdx.x >> 6, lane = threadIdx.x & 63;
    const int r = lane & 15, kg = lane >> 4;
    const int tile0_raw = blockIdx.x * 8 + wid * 2;
    const int tile0 = min(tile0_raw, 48), tile1 = min(tile0_raw + 1, 48);

    const short* Ab = (const short*)aggT + (size_t)sl * HW_ * 64 + kg * 8;
    bf16x8 a0[2], a1[2];
    #pragma unroll
    for (int kk = 0; kk < 2; ++kk) {
        a0[kk] = *(const bf16x8*)(Ab + (size_t)(tile0 * 16 + r) * 64 + kk * 32);
        a1[kk] = *(const bf16x8*)(Ab + (size_t)(tile1 * 16 + r) * 64 + kk * 32);
    }
    #pragma unroll
    for (int kk = 0; kk < 2; ++kk) {
        asm volatile("" : "+v"(a0[kk]));
        asm volatile("" : "+v"(a1[kk]));
    }

    #define STAGE_B(buf, ch) do {                                          \
        if (wid < 2) {                                                     \
            const int slot = wid * 64 + lane;                              \
            const int m = slot >> 3;                                       \
            const int j = (slot & 7) ^ (m & 7);                            \
            const ushort* g = Wsrc + (size_t)((ch) * 16 + m) * 64 + j * 8; \
            ushort* l = &Bs[buf][(size_t)(wid * 64) * 8];                  \
            GL2LDS16(g, l);                                                \
        }                                                                  \
    } while (0)

    const float* dp_b = dsm + (0 * BT_ + sl) * HW_;
    const float* dn_b = dsm + (1 * BT_ + sl) * HW_;
    const float* di_b = dsm + (2 * BT_ + sl) * HW_;

    STAGE_B(0, 0);
    __syncthreads();
    for (int ch = 0; ch < 16; ++ch) {
        const int cur = ch & 1;
        if (ch + 1 < 16) STAGE_B(cur ^ 1, ch + 1);
        f32x4 acc0 = {0.f, 0.f, 0.f, 0.f};
        f32x4 acc1 = {0.f, 0.f, 0.f, 0.f};
        #pragma unroll
        for (int kk = 0; kk < 2; ++kk) {
            const int gidx = (kk * 4 + kg) ^ (r & 7);
            bf16x8 bfr = *(const bf16x8*)&Bs[cur][(size_t)(r * 8 + gidx) * 8];
            acc0 = __builtin_amdgcn_mfma_f32_16x16x32_bf16(a0[kk], bfr, acc0, 0, 0, 0);
            acc1 = __builtin_amdgcn_mfma_f32_16x16x32_bf16(a1[kk], bfr, acc1, 0, 0, 0);
        }
        const int o = ch * 16 + r;
        const float* xb = x1 + (size_t)(b * C_ + o) * TNH;
        auto epi = [&](const f32x4& acc, int tileR) {
            const int n0 = tileR * 16 + kg * 4;
            const f32x4 dp = *(const f32x4*)&dp_b[n0];
            const f32x4 dn = *(const f32x4*)&dn_b[n0];
            const f32x4 di = *(const f32x4*)&di_b[n0];
            const f32x4 xp = *(const f32x4*)&xb[tp * HW_ + n0];
            const f32x4 xn = *(const f32x4*)&xb[tn * HW_ + n0];
            const f32x4 xi = *(const f32x4*)&xb[t * HW_ + n0];
            #pragma unroll
            for (int j = 0; j < 4; ++j) {
                const float feats = (dp[j] * xp[j] + dn[j] * xn[j] + di[j] * xi[j]) * (1.f / 3.f);
                const float fs = fmaxf(acc[j], 0.f) * feats;
                fsT[((size_t)sl * HW_ + n0 + j) * 256 + o] = f2bf(fs);
            }
        };
        if (tile0_raw < 49)     epi(acc0, tile0_raw);
        if (tile0_raw + 1 < 49) epi(acc1, tile0_raw + 1);
        __syncthreads();
    }
    #undef STAGE_B
}

// ---------------- inverse norm + norm over channels ----------------
__global__ __launch_bounds__(256) void k_invnorm(
    const float* __restrict__ x1, float* __restrict__ invn, float* __restrict__ nrm)
{
    __shared__ float sm[4][64];
    const int sl = blockIdx.y, b = sl >> 3, t = sl & 7;
    const int l = threadIdx.x & 63;
    const int cg = threadIdx.x >> 6;
    const int n = blockIdx.x * 64 + l;
    float s = 0.f;
    if (n < HW_) {
        const float* p = x1 + (b * C_ * T_ + t) * HW_ + n;
        for (int c = cg * 64; c < cg * 64 + 64; ++c) {
            const float v = p[c * TNH];
            s = fmaf(v, v, s);
        }
    }
    sm[cg][l] = s;
    __syncthreads();
    if (threadIdx.x < 64 && n < HW_) {
        const float tot = sm[0][l] + sm[1][l] + sm[2][l] + sm[3][l];
        const float nm = fmaxf(sqrtf(tot), 1e-12f);
        nrm[sl * HW_ + n] = nm;
        invn[sl * HW_ + n] = 1.f / nm;
    }
}

// ---------------- nxT: bf16 normalized features, transposed [sl][n][c] ----------------
__global__ __launch_bounds__(256) void k_nxT(
    const float* __restrict__ x1, const float* __restrict__ invn,
    ushort* __restrict__ nxT)
{
    __shared__ float xs[256][17];
    __shared__ float inv_s[16];
    const int sl = blockIdx.y, b = sl >> 3, t = sl & 7;
    const int n0 = blockIdx.x * 16;
    const int tid = threadIdx.x;
    {
        const int n_l = tid & 15;
        const int c0 = tid >> 4;
        const float* p = x1 + (b * C_ * T_ + c0 * T_ + t) * HW_ + n0 + n_l;
        #pragma unroll
        for (int i = 0; i < 16; ++i)
            xs[c0 + 16 * i][n_l] = p[(size_t)16 * i * TNH];
        if (tid < 16) inv_s[tid] = invn[sl * HW_ + n0 + tid];
    }
    __syncthreads();
    const int n_l = tid >> 4;
    const int cq = tid & 15;
    const float inv = inv_s[n_l];
    union { ushort u[16]; uint4 q[2]; } o;
    #pragma unroll
    for (int i = 0; i < 16; ++i)
        o.u[i] = f2bf(xs[cq * 16 + i][n_l] * inv);
    uint4* dst = (uint4*)(nxT + ((size_t)(sl * HW_ + n0 + n_l)) * 256 + cq * 16);
    dst[0] = o.q[0];
    dst[1] = o.q[1];
}

// ---------------- affinity row sum-exp via MFMA, LDS-staged double-buffered B ----------------
__global__ __launch_bounds__(256) void k_affinity_mfma(
    const ushort* __restrict__ nxT, float* __restrict__ sumexp)
{
    __shared__ __align__(16) ushort Bs[2][16 * 256];
    const int sl = blockIdx.y;
    const int s  = blockIdx.z;
    const int b = sl >> 3, t = sl & 7;
    const int t2 = (s == 0) ? (t > 0 ? t - 1 : 0) : (s == 1) ? (t < 7 ? t + 1 : 7) : t;
    const int sl2 = b * 8 + t2;
    const int wid = threadIdx.x >> 6;
    const int lane = threadIdx.x & 63;
    const int r  = lane & 15;
    const int kg = lane >> 4;

    const int tile0_raw = blockIdx.x * 8 + wid * 2;
    const int tile0 = min(tile0_raw, 48);
    const int tile1 = min(tile0_raw + 1, 48);

    const short* Ab = (const short*)nxT + (size_t)sl * HW_ * 256 + kg * 8;
    bf16x8 a0[8], a1[8];
    #pragma unroll
    for (int kk = 0; kk < 8; ++kk) {
        a0[kk] = *(const bf16x8*)(Ab + (size_t)(tile0 * 16 + r) * 256 + kk * 32);
        a1[kk] = *(const bf16x8*)(Ab + (size_t)(tile1 * 16 + r) * 256 + kk * 32);
    }
    #pragma unroll
    for (int kk = 0; kk < 8; ++kk) {
        asm volatile("" : "+v"(a0[kk]));
        asm volatile("" : "+v"(a1[kk]));
    }

    const ushort* Bsrc = nxT + (size_t)sl2 * HW_ * 256;

    #define STAGE_AFF(buf, ch) do {                                           \
        _Pragma("unroll")                                                     \
        for (int e = 0; e < 2; ++e) {                                         \
            const int slot = wid * 128 + e * 64 + lane;                       \
            const int m = slot >> 5;                                          \
            const int j = (slot & 31) ^ (m & 7);                              \
            const ushort* g = Bsrc + (size_t)((ch) * 16 + m) * 256 + j * 8;   \
            ushort* l = &Bs[buf][(size_t)(wid * 128 + e * 64) * 8];           \
            GL2LDS16(g, l);                                                   \
        }                                                                     \
    } while (0)

    float re0[4] = {0.f, 0.f, 0.f, 0.f};
    float re1[4] = {0.f, 0.f, 0.f, 0.f};

    STAGE_AFF(0, 0);
    __syncthreads();
    for (int ch = 0; ch < 49; ++ch) {
        const int cur = ch & 1;
        if (ch + 1 < 49) STAGE_AFF(cur ^ 1, ch + 1);
        f32x4 acc0 = {0.f, 0.f, 0.f, 0.f};
        f32x4 acc1 = {0.f, 0.f, 0.f, 0.f};
        #pragma unroll
        for (int kk = 0; kk < 8; ++kk) {
            const int gidx = (kk * 4 + kg) ^ (r & 7);
            bf16x8 bfr = *(const bf16x8*)&Bs[cur][(size_t)(r * 32 + gidx) * 8];
            acc0 = __builtin_amdgcn_mfma_f32_16x16x32_bf16(a0[kk], bfr, acc0, 0, 0, 0);
            acc1 = __builtin_amdgcn_mfma_f32_16x16x32_bf16(a1[kk], bfr, acc1, 0, 0, 0);
        }
        #pragma unroll
        for (int j = 0; j < 4; ++j) {
            re0[j] += __expf(acc0[j] * TEMP_INV);
            re1[j] += __expf(acc1[j] * TEMP_INV);
        }
        __syncthreads();
    }

    #pragma unroll
    for (int j = 0; j < 4; ++j) {
        float v0 = re0[j], v1 = re1[j];
        v0 += __shfl_xor(v0, 1); v1 += __shfl_xor(v1, 1);
        v0 += __shfl_xor(v0, 2); v1 += __shfl_xor(v1, 2);
        v0 += __shfl_xor(v0, 4); v1 += __shfl_xor(v1, 4);
        v0 += __shfl_xor(v0, 8); v1 += __shfl_xor(v1, 8);
        re0[j] = v0; re1[j] = v1;
    }
    float* dst = sumexp + (s * BT_ + sl) * HW_;
    if ((lane & 15) == 0) {
        if (tile0_raw < 49) {
            #pragma unroll
            for (int j = 0; j < 4; ++j)
                dst[tile0_raw * 16 + kg * 4 + j] = re0[j];
        }
        if (tile0_raw + 1 < 49) {
            #pragma unroll
            for (int j = 0; j < 4; ++j)
                dst[(tile0_raw + 1) * 16 + kg * 4 + j] = re1[j];
        }
    }
    #undef STAGE_AFF
}

// ---------------- diagonal similarity + diag_sm = exp(diag)/sumexp ----------------
__global__ __launch_bounds__(256) void k_diagsm(
    const float* __restrict__ x1, const float* __restrict__ invn,
    const float* __restrict__ sumexp, float* __restrict__ dsm)
{
    __shared__ float sm[3][4][64];
    const int sl = blockIdx.y, b = sl >> 3, t = sl & 7;
    const int l = threadIdx.x & 63;
    const int cg = threadIdx.x >> 6;
    const int n = blockIdx.x * 64 + l;
    const int tp = t > 0 ? t - 1 : 0;
    const int tn = t < 7 ? t + 1 : 7;
    float sp = 0.f, sn2 = 0.f, si = 0.f;
    if (n < HW_) {
        const float* p0 = x1 + (b * C_ * T_ + t) * HW_ + n;
        const float* pp = x1 + (b * C_ * T_ + tp) * HW_ + n;
        const float* pn = x1 + (b * C_ * T_ + tn) * HW_ + n;
        for (int c = cg * 64; c < cg * 64 + 64; ++c) {
            const float v = p0[c * TNH];
            sp  = fmaf(v, pp[c * TNH], sp);
            sn2 = fmaf(v, pn[c * TNH], sn2);
            si  = fmaf(v, v, si);
        }
    }
    sm[0][cg][l] = sp; sm[1][cg][l] = sn2; sm[2][cg][l] = si;
    __syncthreads();
    if (threadIdx.x < 64 && n < HW_) {
        const float d0 = sm[0][0][l] + sm[0][1][l] + sm[0][2][l] + sm[0][3][l];
        const float d1 = sm[1][0][l] + sm[1][1][l] + sm[1][2][l] + sm[1][3][l];
        const float d2 = sm[2][0][l] + sm[2][1][l] + sm[2][2][l] + sm[2][3][l];
        const float it  = invn[sl * HW_ + n];
        const float ip  = invn[(b * T_ + tp) * HW_ + n];
        const float in2 = invn[(b * T_ + tn) * HW_ + n];
        dsm[(0 * BT_ + sl) * HW_ + n] = __expf(d0 * it * ip  * TEMP_INV) / sumexp[(0 * BT_ + sl) * HW_ + n];
        dsm[(1 * BT_ + sl) * HW_ + n] = __expf(d1 * it * in2 * TEMP_INV) / sumexp[(1 * BT_ + sl) * HW_ + n];
        dsm[(2 * BT_ + sl) * HW_ + n] = __expf(d2 * it * it  * TEMP_INV) / sumexp[(2 * BT_ + sl) * HW_ + n];
    }
}

// ---------------- depthwise 3D conv, 3 dilations fused ----------------
__global__ __launch_bounds__(768) void k_dwconv(
    const float* __restrict__ xx, const float* __restrict__ Wsa1,
    const float* __restrict__ Wsa2, const float* __restrict__ Wsa3,
    float* __restrict__ agg)
{
    __shared__ float xp[8 * 1156];
    __shared__ float wl[3][81];
    const int br = blockIdx.x;
    const int r = br & 63;
    const int tid = threadIdx.x;
    const int base = br * TNH;
    for (int i = tid; i < 8 * 1156; i += 768) xp[i] = 0.f;
    if (tid < 243) {
        const int s = tid / 81, k = tid % 81;
        const float* Wp = (s == 0) ? Wsa1 : (s == 1) ? Wsa2 : Wsa3;
        wl[s][k] = Wp[r * 81 + k] * (1.f / 3.f);
    }
    __syncthreads();
    for (int i = tid; i < TNH; i += 768) {
        const int t = i / HW_, p = i - t * HW_;
        const int h = p / 28, w = p - h * 28;
        xp[t * 1156 + (h + 3) * 34 + (w + 3)] = xx[base + i];
    }
    __syncthreads();
    for (int p = tid; p < HW_; p += 768) {
        const int h = p / 28, w = p - h * 28;
        const float* cen = &xp[(h + 3) * 34 + (w + 3)];
        float acc[8] = {0.f, 0.f, 0.f, 0.f, 0.f, 0.f, 0.f, 0.f};
        #pragma unroll
        for (int s = 0; s < 3; ++s) {
            const int d = s + 1;
            #pragma unroll
            for (int kh = 0; kh < 3; ++kh) {
                #pragma unroll
                for (int kw = 0; kw < 3; ++kw) {
                    const int off = (kh - 1) * d * 34 + (kw - 1) * d;
                    float wr[9];
                    #pragma unroll
                    for (int kt = 0; kt < 9; ++kt)
                        wr[kt] = wl[s][kt * 9 + kh * 3 + kw];
                    #pragma unroll
                    for (int ts = 0; ts < 8; ++ts) {
                        const float v = cen[ts * 1156 + off];
                        #pragma unroll
                        for (int kt = 0; kt < 9; ++kt) {
                            const int t = ts + 4 - kt;
                            if (t >= 0 && t < 8)
                                acc[t] = fmaf(v, wr[kt], acc[t]);
                        }
                    }
                }
            }
        }
        #pragma unroll
        for (int t = 0; t < 8; ++t)
            agg[base + t * HW_ + p] = acc[t];
    }
}

// ---------------- BN stats per channel ----------------
__global__ __launch_bounds__(256) void k_bnstats(
    const float* __restrict__ y, const float* __restrict__ gamma,
    const float* __restrict__ beta, float* __restrict__ stats)
{
    __shared__ float sm1[256], sm2[256];
    const int c = blockIdx.x;
    float s1 = 0.f, s2 = 0.f;
    for (int b = 0; b < B_; ++b) {
        const float* p = y + (b * C_ + c) * TNH;
        for (int i = threadIdx.x; i < TNH; i += 256) {
            const float v = p[i];
            s1 += v; s2 = fmaf(v, v, s2);
        }
    }
    sm1[threadIdx.x] = s1; sm2[threadIdx.x] = s2;
    __syncthreads();
    for (int off = 128; off > 0; off >>= 1) {
        if (threadIdx.x < off) {
            sm1[threadIdx.x] += sm1[threadIdx.x + off];
            sm2[threadIdx.x] += sm2[threadIdx.x + off];
        }
        __syncthreads();
    }
    if (threadIdx.x == 0) {
        const float M = (float)(B_ * TNH);
        const float mean = sm1[0] / M;
        const float var = sm2[0] / M - mean * mean;
        const float sc = gamma[c] * rsqrtf(var + 1e-5f);
        stats[c] = sc;
        stats[C_ + c] = beta[c] - mean * sc;
    }
}

// ---------------- BN apply + relu ----------------
__global__ __launch_bounds__(256) void k_bnapply(
    const float* __restrict__ y, const float* __restrict__ stats,
    float* __restrict__ out)
{
    const int total4 = B_ * C_ * TNH / 4;
    for (int i4 = blockIdx.x * 256 + threadIdx.x; i4 < total4; i4 += gridDim.x * 256) {
        float4 v = ((const float4*)y)[i4];
        const int c = (i4 / (TNH / 4)) & 255;
        const float sc = stats[c], bi = stats[C_ + c];
        v.x = fmaxf(fmaf(v.x, sc, bi), 0.f);
        v.y = fmaxf(fmaf(v.y, sc, bi), 0.f);
        v.z = fmaxf(fmaf(v.z, sc, bi), 0.f);
        v.w = fmaxf(fmaf(v.w, sc, bi), 0.f);
        ((float4*)out)[i4] = v;
    }
}

extern "C" void kernel_launch(void* const* d_in, const int* in_sizes, int n_in,
                              void* d_out, int out_size, void* d_ws, size_t ws_size,
                              hipStream_t stream) {
    (void)in_sizes; (void)n_in; (void)out_size; (void)ws_size;
    const float* x      = (const float*)d_in[0];
    const float* W_dc2  = (const float*)d_in[1];
    const float* W_up2  = (const float*)d_in[2];
    const float* W_dc   = (const float*)d_in[3];
    const float* Wsa1   = (const float*)d_in[4];
    const float* Wsa2   = (const float*)d_in[5];
    const float* Wsa3   = (const float*)d_in[6];
    const float* W_back = (const float*)d_in[7];
    const float* gamma  = (const float*)d_in[8];
    const float* beta   = (const float*)d_in[9];
    float* out = (float*)d_out;
    float* ws  = (float*)d_ws;

    const size_t NE = (size_t)B_ * C_ * TNH;        // 6,422,528
    const size_t NR = (size_t)B_ * RC_ * TNH;       // 1,605,632
    float* x1     = ws;                             // NE (x1, later y)
    ushort* nxT   = (ushort*)(ws + NE);             // NE ushorts
    ushort* xT    = (ushort*)(ws + NE + NE / 2);    // NE ushorts (later fsT)
    float* xx     = ws + 2 * NE;                    // NR
    float* agg    = xx + NR;                        // NR
    ushort* aggT  = (ushort*)(agg + NR);            // NR ushorts
    float* invn   = agg + NR + NR / 2;              // 25088
    float* nrm    = invn + (size_t)BT_ * HW_;       // 25088
    float* sumexp = nrm + (size_t)BT_ * HW_;        // 75264
    float* dsm    = sumexp + 3 * (size_t)BT_ * HW_; // 75264
    float* stats  = dsm + 3 * (size_t)BT_ * HW_;    // 512
    ushort* Wbf   = (ushort*)(stats + 512);         // 163840 ushorts
    ushort* fsT   = xT;

    // 0. weights -> bf16
    k_wcvt<<<640, 256, 0, stream>>>(W_dc2, W_up2, W_dc, W_back, Wbf);
    // 1. xT = bf16 transpose of x
    k_xpose<<<dim3(49, 32), 256, 0, stream>>>(x, xT);
    // 2. x1 = W_dc2 @ x   (MFMA, channel-major fp32 out)
    k_gemm_cm<16, 8, 0><<<dim3(7, 32), 256, 0, stream>>>(Wbf, xT, x1, nullptr);
    // 3. invnorm + norm
    k_invnorm<<<dim3(13, 32), 256, 0, stream>>>(x1, invn, nrm);
    // 4. nxT = bf16(x1 * invn) transposed
    k_nxT<<<dim3(49, 32), 256, 0, stream>>>(x1, invn, nxT);
    // 5. affinity sum-exp (3 shifts)
    k_affinity_mfma<<<dim3(7, 32, 3), 256, 0, stream>>>(nxT, sumexp);
    // 6. diag_sm
    k_diagsm<<<dim3(13, 32), 256, 0, stream>>>(x1, invn, sumexp, dsm);
    // 7. xx = norm * (W_dc @ nx)  (MFMA, M=64)
    k_gemm_cm<4, 8, 1><<<dim3(7, 32), 256, 0, stream>>>(Wbf + 131072, nxT, xx, nrm);
    // 8. agg = mean of 3 dilated dwconvs
    k_dwconv<<<256, 768, 0, stream>>>(xx, Wsa1, Wsa2, Wsa3, agg);
    // 9. aggT = bf16 transpose of agg
    k_xpose64<<<dim3(49, 32), 256, 0, stream>>>(agg, aggT);
    // 10. fsT = bf16( relu(W_back @ aggT) * feats )  (K=64 MFMA, fused epilogue)
    k_gemm_fs<<<dim3(7, 32), 256, 0, stream>>>(Wbf + 147456, aggT, x1, dsm, fsT);
    // 11. y = x + W_up2 @ fsT  (MFMA, residual) -> overwrite x1 buffer
    k_gemm_cm<16, 8, 2><<<dim3(7, 32), 256, 0, stream>>>(Wbf + 65536, fsT, x1, x);
    // 12. BN stats
    k_bnstats<<<256, 256, 0, stream>>>(x1, gamma, beta, stats);
    // 13. BN apply + relu -> out
    k_bnapply<<<2048, 256, 0, stream>>>(x1, stats, out);
}

// Round 6
// 259.559 us; speedup vs baseline: 5.3752x; 1.2459x over previous
//
#include <hip/hip_runtime.h>

#define B_ 4
#define C_ 256
#define T_ 8
#define HW_ 784
#define RC_ 64
#define TNH (T_*HW_)   // 6272
#define BT_ (B_*T_)    // 32
#define TEMP_INV 14.28571428571f  // 1/0.07

typedef __attribute__((ext_vector_type(8))) short bf16x8;
typedef __attribute__((ext_vector_type(4))) float f32x4;

__device__ __forceinline__ ushort f2bf(float f) {
    uint x = __float_as_uint(f);
    uint r = (x + 0x7FFFu + ((x >> 16) & 1u)) >> 16;   // RNE
    return (ushort)r;
}

#define GL2LDS16(g, l) __builtin_amdgcn_global_load_lds( \
    (const __attribute__((address_space(1))) void*)(g), \
    (__attribute__((address_space(3))) void*)(l), 16, 0, 0)

// ---------------- weight fp32 -> bf16 (all four, packed into one buffer) ----------------
// layout (ushort idx): [0,65536) W_dc2 | [65536,131072) W_up2 | [131072,147456) W_dc | [147456,163840) W_back
__global__ __launch_bounds__(256) void k_wcvt(
    const float* __restrict__ w_dc2, const float* __restrict__ w_up2,
    const float* __restrict__ w_dc, const float* __restrict__ w_back,
    ushort* __restrict__ dst)
{
    const int idx = blockIdx.x * 256 + threadIdx.x;
    if (idx >= 163840) return;
    float v;
    if (idx < 65536)       v = w_dc2[idx];
    else if (idx < 131072) v = w_up2[idx - 65536];
    else if (idx < 147456) v = w_dc[idx - 131072];
    else                   v = w_back[idx - 147456];
    dst[idx] = f2bf(v);
}

// ---------------- transpose fp32 [b][256][t][n] -> bf16 [sl][n][256] ----------------
__global__ __launch_bounds__(256) void k_xpose(
    const float* __restrict__ X, ushort* __restrict__ XT)
{
    __shared__ float xs[256][17];
    const int sl = blockIdx.y, b = sl >> 3, t = sl & 7;
    const int n0 = blockIdx.x * 16;
    const int tid = threadIdx.x;
    {
        const int n_l = tid & 15;
        const int c0 = tid >> 4;
        const float* p = X + (b * C_ * T_ + c0 * T_ + t) * HW_ + n0 + n_l;
        #pragma unroll
        for (int i = 0; i < 16; ++i)
            xs[c0 + 16 * i][n_l] = p[(size_t)16 * i * TNH];
    }
    __syncthreads();
    const int n_l = tid >> 4;
    const int cq = tid & 15;
    union { ushort u[16]; uint4 q[2]; } o;
    #pragma unroll
    for (int i = 0; i < 16; ++i)
        o.u[i] = f2bf(xs[cq * 16 + i][n_l]);
    uint4* dst = (uint4*)(XT + ((size_t)(sl * HW_ + n0 + n_l)) * 256 + cq * 16);
    dst[0] = o.q[0];
    dst[1] = o.q[1];
}

// ---------------- transpose fp32 agg [b][64][t][n] -> bf16 [sl][n][64] ----------------
__global__ __launch_bounds__(256) void k_xpose64(
    const float* __restrict__ A, ushort* __restrict__ AT)
{
    __shared__ float xs[64][17];
    const int sl = blockIdx.y, b = sl >> 3, t = sl & 7;
    const int n0 = blockIdx.x * 16;
    const int tid = threadIdx.x;
    {
        const int n_l = tid & 15;
        const int c0 = tid >> 4;
        #pragma unroll
        for (int i = 0; i < 4; ++i)
            xs[c0 + 16 * i][n_l] = A[((size_t)(b * RC_ + c0 + 16 * i) * T_ + t) * HW_ + n0 + n_l];
    }
    __syncthreads();
    const int n_l = tid >> 4;
    const int cq = tid & 15;
    union { ushort u[4]; uint2 q; } o;
    #pragma unroll
    for (int i = 0; i < 4; ++i)
        o.u[i] = f2bf(xs[cq * 4 + i][n_l]);
    *(uint2*)(AT + ((size_t)(sl * HW_ + n0 + n_l)) * 64 + cq * 4) = o.q;
}

// ---------------- generic MFMA conv1x1, channel-major fp32 output ----------------
// MODE 0: plain.  MODE 1: *= aux[sl*HW+n] (norm).  MODE 2: += aux (x residual, C=256).
template<int MCH, int KK, int MODE>
__global__ __launch_bounds__(256) void k_gemm_cm(
    const ushort* __restrict__ Wsrc, const ushort* __restrict__ XT,
    float* __restrict__ Y, const float* __restrict__ aux)
{
    constexpr int KD = KK * 32;
    constexpr int GPR = KD / 8;
    constexpr int M = MCH * 16;
    __shared__ __align__(16) ushort Bs[2][16 * KD];
    const int sl = blockIdx.y, b = sl >> 3, t = sl & 7;
    const int wid = threadIdx.x >> 6, lane = threadIdx.x & 63;
    const int r = lane & 15, kg = lane >> 4;
    const int tile0_raw = blockIdx.x * 8 + wid * 2;
    const int tile0 = min(tile0_raw, 48), tile1 = min(tile0_raw + 1, 48);

    const short* Ab = (const short*)XT + (size_t)sl * HW_ * KD + kg * 8;
    bf16x8 a0[KK], a1[KK];
    #pragma unroll
    for (int kk = 0; kk < KK; ++kk) {
        a0[kk] = *(const bf16x8*)(Ab + (size_t)(tile0 * 16 + r) * KD + kk * 32);
        a1[kk] = *(const bf16x8*)(Ab + (size_t)(tile1 * 16 + r) * KD + kk * 32);
    }
    #pragma unroll
    for (int kk = 0; kk < KK; ++kk) {
        asm volatile("" : "+v"(a0[kk]));
        asm volatile("" : "+v"(a1[kk]));
    }

    f32x4 nrm0, nrm1;
    if (MODE == 1) {
        nrm0 = *(const f32x4*)&aux[sl * HW_ + tile0 * 16 + kg * 4];
        nrm1 = *(const f32x4*)&aux[sl * HW_ + tile1 * 16 + kg * 4];
    }

    #define STAGE_W(buf, ch) do {                                              \
        if (KK == 8) {                                                         \
            _Pragma("unroll")                                                  \
            for (int e = 0; e < 2; ++e) {                                      \
                const int slot = wid * 128 + e * 64 + lane;                    \
                const int m = slot >> 5;                                       \
                const int j = (slot & 31) ^ (m & 7);                           \
                const ushort* g = Wsrc + (size_t)((ch) * 16 + m) * KD + j * 8; \
                ushort* l = &Bs[buf][(size_t)(wid * 128 + e * 64) * 8];        \
                GL2LDS16(g, l);                                                \
            }                                                                  \
        } else {                                                               \
            if (wid < 2) {                                                     \
                const int slot = wid * 64 + lane;                              \
                const int m = slot >> 3;                                       \
                const int j = (slot & 7) ^ (m & 7);                            \
                const ushort* g = Wsrc + (size_t)((ch) * 16 + m) * KD + j * 8; \
                ushort* l = &Bs[buf][(size_t)(wid * 64) * 8];                  \
                GL2LDS16(g, l);                                                \
            }                                                                  \
        }                                                                      \
    } while (0)

    STAGE_W(0, 0);
    __syncthreads();
    for (int ch = 0; ch < MCH; ++ch) {
        const int cur = ch & 1;
        if (ch + 1 < MCH) STAGE_W(cur ^ 1, ch + 1);
        f32x4 acc0 = {0.f, 0.f, 0.f, 0.f};
        f32x4 acc1 = {0.f, 0.f, 0.f, 0.f};
        #pragma unroll
        for (int kk = 0; kk < KK; ++kk) {
            const int gidx = (kk * 4 + kg) ^ (r & 7);
            bf16x8 bfr = *(const bf16x8*)&Bs[cur][(size_t)(r * GPR + gidx) * 8];
            acc0 = __builtin_amdgcn_mfma_f32_16x16x32_bf16(a0[kk], bfr, acc0, 0, 0, 0);
            acc1 = __builtin_amdgcn_mfma_f32_16x16x32_bf16(a1[kk], bfr, acc1, 0, 0, 0);
        }
        const int o = ch * 16 + r;
        const size_t ybase = ((size_t)(b * M + o) * T_ + t) * HW_;
        if (tile0_raw < 49) {
            const int n0 = tile0_raw * 16 + kg * 4;
            f32x4 v = acc0;
            if (MODE == 1) v *= nrm0;
            if (MODE == 2) v += *(const f32x4*)&aux[((size_t)(b * C_ + o) * T_ + t) * HW_ + n0];
            *(f32x4*)&Y[ybase + n0] = v;
        }
        if (tile0_raw + 1 < 49) {
            const int n0 = (tile0_raw + 1) * 16 + kg * 4;
            f32x4 v = acc1;
            if (MODE == 1) v *= nrm1;
            if (MODE == 2) v += *(const f32x4*)&aux[((size_t)(b * C_ + o) * T_ + t) * HW_ + n0];
            *(f32x4*)&Y[ybase + n0] = v;
        }
        __syncthreads();
    }
    #undef STAGE_W
}

// ---------------- score GEMM (K=64) with fused relu*feats epilogue -> fsT bf16 [sl][n][256] ----------------
__global__ __launch_bounds__(256) void k_gemm_fs(
    const ushort* __restrict__ Wsrc, const ushort* __restrict__ aggT,
    const float* __restrict__ x1, const float* __restrict__ dsm,
    ushort* __restrict__ fsT)
{
    __shared__ __align__(16) ushort Bs[2][16 * 64];
    const int sl = blockIdx.y, b = sl >> 3, t = sl & 7;
    const int tp = t > 0 ? t - 1 : 0;
    const int tn = t < 7 ? t + 1 : 7;
    const int wid = threadIdx.x >> 6, lane = threadIdx.x & 63;
    const int r = lane & 15, kg = lane >> 4;
    const int tile0_raw = blockIdx.x * 8 + wid * 2;
    const int tile0 = min(tile0_raw, 48), tile1 = min(tile0_raw + 1, 48);

    const short* Ab = (const short*)aggT + (size_t)sl * HW_ * 64 + kg * 8;
    bf16x8 a0[2], a1[2];
    #pragma unroll
    for (int kk = 0; kk < 2; ++kk) {
        a0[kk] = *(const bf16x8*)(Ab + (size_t)(tile0 * 16 + r) * 64 + kk * 32);
        a1[kk] = *(const bf16x8*)(Ab + (size_t)(tile1 * 16 + r) * 64 + kk * 32);
    }
    #pragma unroll
    for (int kk = 0; kk < 2; ++kk) {
        asm volatile("" : "+v"(a0[kk]));
        asm volatile("" : "+v"(a1[kk]));
    }

    #define STAGE_B(buf, ch) do {                                          \
        if (wid < 2) {                                                     \
            const int slot = wid * 64 + lane;                              \
            const int m = slot >> 3;                                       \
            const int j = (slot & 7) ^ (m & 7);                            \
            const ushort* g = Wsrc + (size_t)((ch) * 16 + m) * 64 + j * 8; \
            ushort* l = &Bs[buf][(size_t)(wid * 64) * 8];                  \
            GL2LDS16(g, l);                                                \
        }                                                                  \
    } while (0)

    const float* dp_b = dsm + (0 * BT_ + sl) * HW_;
    const float* dn_b = dsm + (1 * BT_ + sl) * HW_;
    const float* di_b = dsm + (2 * BT_ + sl) * HW_;

    STAGE_B(0, 0);
    __syncthreads();
    for (int ch = 0; ch < 16; ++ch) {
        const int cur = ch & 1;
        if (ch + 1 < 16) STAGE_B(cur ^ 1, ch + 1);
        f32x4 acc0 = {0.f, 0.f, 0.f, 0.f};
        f32x4 acc1 = {0.f, 0.f, 0.f, 0.f};
        #pragma unroll
        for (int kk = 0; kk < 2; ++kk) {
            const int gidx = (kk * 4 + kg) ^ (r & 7);
            bf16x8 bfr = *(const bf16x8*)&Bs[cur][(size_t)(r * 8 + gidx) * 8];
            acc0 = __builtin_amdgcn_mfma_f32_16x16x32_bf16(a0[kk], bfr, acc0, 0, 0, 0);
            acc1 = __builtin_amdgcn_mfma_f32_16x16x32_bf16(a1[kk], bfr, acc1, 0, 0, 0);
        }
        const int o = ch * 16 + r;
        const float* xb = x1 + (size_t)(b * C_ + o) * TNH;
        auto epi = [&](const f32x4& acc, int tileR) {
            const int n0 = tileR * 16 + kg * 4;
            const f32x4 dp = *(const f32x4*)&dp_b[n0];
            const f32x4 dn = *(const f32x4*)&dn_b[n0];
            const f32x4 di = *(const f32x4*)&di_b[n0];
            const f32x4 xp = *(const f32x4*)&xb[tp * HW_ + n0];
            const f32x4 xn = *(const f32x4*)&xb[tn * HW_ + n0];
            const f32x4 xi = *(const f32x4*)&xb[t * HW_ + n0];
            #pragma unroll
            for (int j = 0; j < 4; ++j) {
                const float feats = (dp[j] * xp[j] + dn[j] * xn[j] + di[j] * xi[j]) * (1.f / 3.f);
                const float fs = fmaxf(acc[j], 0.f) * feats;
                fsT[((size_t)sl * HW_ + n0 + j) * 256 + o] = f2bf(fs);
            }
        };
        if (tile0_raw < 49)     epi(acc0, tile0_raw);
        if (tile0_raw + 1 < 49) epi(acc1, tile0_raw + 1);
        __syncthreads();
    }
    #undef STAGE_B
}

// ---------------- inverse norm + norm over channels ----------------
__global__ __launch_bounds__(256) void k_invnorm(
    const float* __restrict__ x1, float* __restrict__ invn, float* __restrict__ nrm)
{
    __shared__ float sm[4][64];
    const int sl = blockIdx.y, b = sl >> 3, t = sl & 7;
    const int l = threadIdx.x & 63;
    const int cg = threadIdx.x >> 6;
    const int n = blockIdx.x * 64 + l;
    float s = 0.f;
    if (n < HW_) {
        const float* p = x1 + (b * C_ * T_ + t) * HW_ + n;
        for (int c = cg * 64; c < cg * 64 + 64; ++c) {
            const float v = p[c * TNH];
            s = fmaf(v, v, s);
        }
    }
    sm[cg][l] = s;
    __syncthreads();
    if (threadIdx.x < 64 && n < HW_) {
        const float tot = sm[0][l] + sm[1][l] + sm[2][l] + sm[3][l];
        const float nm = fmaxf(sqrtf(tot), 1e-12f);
        nrm[sl * HW_ + n] = nm;
        invn[sl * HW_ + n] = 1.f / nm;
    }
}

// ---------------- nxT: bf16 normalized features, transposed [sl][n][c] ----------------
__global__ __launch_bounds__(256) void k_nxT(
    const float* __restrict__ x1, const float* __restrict__ invn,
    ushort* __restrict__ nxT)
{
    __shared__ float xs[256][17];
    __shared__ float inv_s[16];
    const int sl = blockIdx.y, b = sl >> 3, t = sl & 7;
    const int n0 = blockIdx.x * 16;
    const int tid = threadIdx.x;
    {
        const int n_l = tid & 15;
        const int c0 = tid >> 4;
        const float* p = x1 + (b * C_ * T_ + c0 * T_ + t) * HW_ + n0 + n_l;
        #pragma unroll
        for (int i = 0; i < 16; ++i)
            xs[c0 + 16 * i][n_l] = p[(size_t)16 * i * TNH];
        if (tid < 16) inv_s[tid] = invn[sl * HW_ + n0 + tid];
    }
    __syncthreads();
    const int n_l = tid >> 4;
    const int cq = tid & 15;
    const float inv = inv_s[n_l];
    union { ushort u[16]; uint4 q[2]; } o;
    #pragma unroll
    for (int i = 0; i < 16; ++i)
        o.u[i] = f2bf(xs[cq * 16 + i][n_l] * inv);
    uint4* dst = (uint4*)(nxT + ((size_t)(sl * HW_ + n0 + n_l)) * 256 + cq * 16);
    dst[0] = o.q[0];
    dst[1] = o.q[1];
}

// ---------------- affinity row sum-exp via MFMA, LDS-staged double-buffered B ----------------
__global__ __launch_bounds__(256) void k_affinity_mfma(
    const ushort* __restrict__ nxT, float* __restrict__ sumexp)
{
    __shared__ __align__(16) ushort Bs[2][16 * 256];
    const int sl = blockIdx.y;
    const int s  = blockIdx.z;
    const int b = sl >> 3, t = sl & 7;
    const int t2 = (s == 0) ? (t > 0 ? t - 1 : 0) : (s == 1) ? (t < 7 ? t + 1 : 7) : t;
    const int sl2 = b * 8 + t2;
    const int wid = threadIdx.x >> 6;
    const int lane = threadIdx.x & 63;
    const int r  = lane & 15;
    const int kg = lane >> 4;

    const int tile0_raw = blockIdx.x * 8 + wid * 2;
    const int tile0 = min(tile0_raw, 48);
    const int tile1 = min(tile0_raw + 1, 48);

    const short* Ab = (const short*)nxT + (size_t)sl * HW_ * 256 + kg * 8;
    bf16x8 a0[8], a1[8];
    #pragma unroll
    for (int kk = 0; kk < 8; ++kk) {
        a0[kk] = *(const bf16x8*)(Ab + (size_t)(tile0 * 16 + r) * 256 + kk * 32);
        a1[kk] = *(const bf16x8*)(Ab + (size_t)(tile1 * 16 + r) * 256 + kk * 32);
    }
    #pragma unroll
    for (int kk = 0; kk < 8; ++kk) {
        asm volatile("" : "+v"(a0[kk]));
        asm volatile("" : "+v"(a1[kk]));
    }

    const ushort* Bsrc = nxT + (size_t)sl2 * HW_ * 256;

    #define STAGE_AFF(buf, ch) do {                                           \
        _Pragma("unroll")                                                     \
        for (int e = 0; e < 2; ++e) {                                         \
            const int slot = wid * 128 + e * 64 + lane;                       \
            const int m = slot >> 5;                                          \
            const int j = (slot & 31) ^ (m & 7);                              \
            const ushort* g = Bsrc + (size_t)((ch) * 16 + m) * 256 + j * 8;   \
            ushort* l = &Bs[buf][(size_t)(wid * 128 + e * 64) * 8];           \
            GL2LDS16(g, l);                                                   \
        }                                                                     \
    } while (0)

    float re0[4] = {0.f, 0.f, 0.f, 0.f};
    float re1[4] = {0.f, 0.f, 0.f, 0.f};

    STAGE_AFF(0, 0);
    __syncthreads();
    for (int ch = 0; ch < 49; ++ch) {
        const int cur = ch & 1;
        if (ch + 1 < 49) STAGE_AFF(cur ^ 1, ch + 1);
        f32x4 acc0 = {0.f, 0.f, 0.f, 0.f};
        f32x4 acc1 = {0.f, 0.f, 0.f, 0.f};
        #pragma unroll
        for (int kk = 0; kk < 8; ++kk) {
            const int gidx = (kk * 4 + kg) ^ (r & 7);
            bf16x8 bfr = *(const bf16x8*)&Bs[cur][(size_t)(r * 32 + gidx) * 8];
            acc0 = __builtin_amdgcn_mfma_f32_16x16x32_bf16(a0[kk], bfr, acc0, 0, 0, 0);
            acc1 = __builtin_amdgcn_mfma_f32_16x16x32_bf16(a1[kk], bfr, acc1, 0, 0, 0);
        }
        #pragma unroll
        for (int j = 0; j < 4; ++j) {
            re0[j] += __expf(acc0[j] * TEMP_INV);
            re1[j] += __expf(acc1[j] * TEMP_INV);
        }
        __syncthreads();
    }

    #pragma unroll
    for (int j = 0; j < 4; ++j) {
        float v0 = re0[j], v1 = re1[j];
        v0 += __shfl_xor(v0, 1); v1 += __shfl_xor(v1, 1);
        v0 += __shfl_xor(v0, 2); v1 += __shfl_xor(v1, 2);
        v0 += __shfl_xor(v0, 4); v1 += __shfl_xor(v1, 4);
        v0 += __shfl_xor(v0, 8); v1 += __shfl_xor(v1, 8);
        re0[j] = v0; re1[j] = v1;
    }
    float* dst = sumexp + (s * BT_ + sl) * HW_;
    if ((lane & 15) == 0) {
        if (tile0_raw < 49) {
            #pragma unroll
            for (int j = 0; j < 4; ++j)
                dst[tile0_raw * 16 + kg * 4 + j] = re0[j];
        }
        if (tile0_raw + 1 < 49) {
            #pragma unroll
            for (int j = 0; j < 4; ++j)
                dst[(tile0_raw + 1) * 16 + kg * 4 + j] = re1[j];
        }
    }
    #undef STAGE_AFF
}

// ---------------- diagonal similarity + diag_sm = exp(diag)/sumexp ----------------
__global__ __launch_bounds__(256) void k_diagsm(
    const float* __restrict__ x1, const float* __restrict__ invn,
    const float* __restrict__ sumexp, float* __restrict__ dsm)
{
    __shared__ float sm[3][4][64];
    const int sl = blockIdx.y, b = sl >> 3, t = sl & 7;
    const int l = threadIdx.x & 63;
    const int cg = threadIdx.x >> 6;
    const int n = blockIdx.x * 64 + l;
    const int tp = t > 0 ? t - 1 : 0;
    const int tn = t < 7 ? t + 1 : 7;
    float sp = 0.f, sn2 = 0.f, si = 0.f;
    if (n < HW_) {
        const float* p0 = x1 + (b * C_ * T_ + t) * HW_ + n;
        const float* pp = x1 + (b * C_ * T_ + tp) * HW_ + n;
        const float* pn = x1 + (b * C_ * T_ + tn) * HW_ + n;
        for (int c = cg * 64; c < cg * 64 + 64; ++c) {
            const float v = p0[c * TNH];
            sp  = fmaf(v, pp[c * TNH], sp);
            sn2 = fmaf(v, pn[c * TNH], sn2);
            si  = fmaf(v, v, si);
        }
    }
    sm[0][cg][l] = sp; sm[1][cg][l] = sn2; sm[2][cg][l] = si;
    __syncthreads();
    if (threadIdx.x < 64 && n < HW_) {
        const float d0 = sm[0][0][l] + sm[0][1][l] + sm[0][2][l] + sm[0][3][l];
        const float d1 = sm[1][0][l] + sm[1][1][l] + sm[1][2][l] + sm[1][3][l];
        const float d2 = sm[2][0][l] + sm[2][1][l] + sm[2][2][l] + sm[2][3][l];
        const float it  = invn[sl * HW_ + n];
        const float ip  = invn[(b * T_ + tp) * HW_ + n];
        const float in2 = invn[(b * T_ + tn) * HW_ + n];
        dsm[(0 * BT_ + sl) * HW_ + n] = __expf(d0 * it * ip  * TEMP_INV) / sumexp[(0 * BT_ + sl) * HW_ + n];
        dsm[(1 * BT_ + sl) * HW_ + n] = __expf(d1 * it * in2 * TEMP_INV) / sumexp[(1 * BT_ + sl) * HW_ + n];
        dsm[(2 * BT_ + sl) * HW_ + n] = __expf(d2 * it * it  * TEMP_INV) / sumexp[(2 * BT_ + sl) * HW_ + n];
    }
}

// ---------------- depthwise 3D conv, 3 dilations fused ----------------
// Block = (b,r,half): stages zero-padded half-volume [8][20*34] (21.8 KB),
// 448 threads, 392 pixels -> single pass, all 8 t-outputs in registers.
// Dilation loop kept runtime (body ~1/3 size, I$-resident).
__global__ __launch_bounds__(448) void k_dwconv(
    const float* __restrict__ xx, const float* __restrict__ Wsa1,
    const float* __restrict__ Wsa2, const float* __restrict__ Wsa3,
    float* __restrict__ agg)
{
    __shared__ float xp[8 * 680];    // [t][row(20)*34 + col+3], 21760 B
    __shared__ float wl[3][81];
    const int br = blockIdx.x >> 1;  // b*RC + r
    const int half = blockIdx.x & 1;
    const int h0 = half * 14;
    const int r = br & 63;
    const int tid = threadIdx.x;
    const int base = br * TNH;
    for (int i = tid; i < 8 * 680; i += 448) xp[i] = 0.f;
    if (tid < 243) {
        const int s = tid / 81, k = tid % 81;
        const float* Wp = (s == 0) ? Wsa1 : (s == 1) ? Wsa2 : Wsa3;
        wl[s][k] = Wp[r * 81 + k] * (1.f / 3.f);
    }
    __syncthreads();
    // load rows h0-3 .. h0+16 (valid ones), cols 0..27 -> xp[t][row*34 + col+3]
    for (int i = tid; i < 8 * 20 * 28; i += 448) {
        const int t = i / 560;
        const int rem = i - t * 560;
        const int row = rem / 28, col = rem - row * 28;
        const int hh = h0 - 3 + row;
        if (hh >= 0 && hh < 28)
            xp[t * 680 + row * 34 + col + 3] = xx[base + t * HW_ + hh * 28 + col];
    }
    __syncthreads();
    if (tid < 392) {
        const int hl = tid / 28, w = tid - hl * 28;   // local h 0..13
        const float* cen = &xp[(hl + 3) * 34 + (w + 3)];
        float acc[8] = {0.f, 0.f, 0.f, 0.f, 0.f, 0.f, 0.f, 0.f};
        for (int s = 0; s < 3; ++s) {                 // runtime dilation loop
            const int d = s + 1;
            #pragma unroll
            for (int kh = 0; kh < 3; ++kh) {
                #pragma unroll
                for (int kw = 0; kw < 3; ++kw) {
                    const int off = (kh - 1) * d * 34 + (kw - 1) * d;
                    float wr[9];
                    #pragma unroll
                    for (int kt = 0; kt < 9; ++kt)
                        wr[kt] = wl[s][kt * 9 + kh * 3 + kw];
                    #pragma unroll
                    for (int ts = 0; ts < 8; ++ts) {
                        const float v = cen[ts * 680 + off];
                        #pragma unroll
                        for (int kt = 0; kt < 9; ++kt) {
                            const int t = ts + 4 - kt;   // output t receiving this tap
                            if (t >= 0 && t < 8)
                                acc[t] = fmaf(v, wr[kt], acc[t]);
                        }
                    }
                }
            }
        }
        const int p = h0 * 28 + tid;
        #pragma unroll
        for (int t = 0; t < 8; ++t)
            agg[base + t * HW_ + p] = acc[t];
    }
}

// ---------------- BN stats per channel ----------------
__global__ __launch_bounds__(256) void k_bnstats(
    const float* __restrict__ y, const float* __restrict__ gamma,
    const float* __restrict__ beta, float* __restrict__ stats)
{
    __shared__ float sm1[256], sm2[256];
    const int c = blockIdx.x;
    float s1 = 0.f, s2 = 0.f;
    for (int b = 0; b < B_; ++b) {
        const float* p = y + (b * C_ + c) * TNH;
        for (int i = threadIdx.x; i < TNH; i += 256) {
            const float v = p[i];
            s1 += v; s2 = fmaf(v, v, s2);
        }
    }
    sm1[threadIdx.x] = s1; sm2[threadIdx.x] = s2;
    __syncthreads();
    for (int off = 128; off > 0; off >>= 1) {
        if (threadIdx.x < off) {
            sm1[threadIdx.x] += sm1[threadIdx.x + off];
            sm2[threadIdx.x] += sm2[threadIdx.x + off];
        }
        __syncthreads();
    }
    if (threadIdx.x == 0) {
        const float M = (float)(B_ * TNH);
        const float mean = sm1[0] / M;
        const float var = sm2[0] / M - mean * mean;
        const float sc = gamma[c] * rsqrtf(var + 1e-5f);
        stats[c] = sc;
        stats[C_ + c] = beta[c] - mean * sc;
    }
}

// ---------------- BN apply + relu ----------------
__global__ __launch_bounds__(256) void k_bnapply(
    const float* __restrict__ y, const float* __restrict__ stats,
    float* __restrict__ out)
{
    const int total4 = B_ * C_ * TNH / 4;
    for (int i4 = blockIdx.x * 256 + threadIdx.x; i4 < total4; i4 += gridDim.x * 256) {
        float4 v = ((const float4*)y)[i4];
        const int c = (i4 / (TNH / 4)) & 255;
        const float sc = stats[c], bi = stats[C_ + c];
        v.x = fmaxf(fmaf(v.x, sc, bi), 0.f);
        v.y = fmaxf(fmaf(v.y, sc, bi), 0.f);
        v.z = fmaxf(fmaf(v.z, sc, bi), 0.f);
        v.w = fmaxf(fmaf(v.w, sc, bi), 0.f);
        ((float4*)out)[i4] = v;
    }
}

extern "C" void kernel_launch(void* const* d_in, const int* in_sizes, int n_in,
                              void* d_out, int out_size, void* d_ws, size_t ws_size,
                              hipStream_t stream) {
    (void)in_sizes; (void)n_in; (void)out_size; (void)ws_size;
    const float* x      = (const float*)d_in[0];
    const float* W_dc2  = (const float*)d_in[1];
    const float* W_up2  = (const float*)d_in[2];
    const float* W_dc   = (const float*)d_in[3];
    const float* Wsa1   = (const float*)d_in[4];
    const float* Wsa2   = (const float*)d_in[5];
    const float* Wsa3   = (const float*)d_in[6];
    const float* W_back = (const float*)d_in[7];
    const float* gamma  = (const float*)d_in[8];
    const float* beta   = (const float*)d_in[9];
    float* out = (float*)d_out;
    float* ws  = (float*)d_ws;

    const size_t NE = (size_t)B_ * C_ * TNH;        // 6,422,528
    const size_t NR = (size_t)B_ * RC_ * TNH;       // 1,605,632
    float* x1     = ws;                             // NE (x1, later y)
    ushort* nxT   = (ushort*)(ws + NE);             // NE ushorts
    ushort* xT    = (ushort*)(ws + NE + NE / 2);    // NE ushorts (later fsT)
    float* xx     = ws + 2 * NE;                    // NR
    float* agg    = xx + NR;                        // NR
    ushort* aggT  = (ushort*)(agg + NR);            // NR ushorts
    float* invn   = agg + NR + NR / 2;              // 25088
    float* nrm    = invn + (size_t)BT_ * HW_;       // 25088
    float* sumexp = nrm + (size_t)BT_ * HW_;        // 75264
    float* dsm    = sumexp + 3 * (size_t)BT_ * HW_; // 75264
    float* stats  = dsm + 3 * (size_t)BT_ * HW_;    // 512
    ushort* Wbf   = (ushort*)(stats + 512);         // 163840 ushorts
    ushort* fsT   = xT;

    // 0. weights -> bf16
    k_wcvt<<<640, 256, 0, stream>>>(W_dc2, W_up2, W_dc, W_back, Wbf);
    // 1. xT = bf16 transpose of x
    k_xpose<<<dim3(49, 32), 256, 0, stream>>>(x, xT);
    // 2. x1 = W_dc2 @ x   (MFMA, channel-major fp32 out)
    k_gemm_cm<16, 8, 0><<<dim3(7, 32), 256, 0, stream>>>(Wbf, xT, x1, nullptr);
    // 3. invnorm + norm
    k_invnorm<<<dim3(13, 32), 256, 0, stream>>>(x1, invn, nrm);
    // 4. nxT = bf16(x1 * invn) transposed
    k_nxT<<<dim3(49, 32), 256, 0, stream>>>(x1, invn, nxT);
    // 5. affinity sum-exp (3 shifts)
    k_affinity_mfma<<<dim3(7, 32, 3), 256, 0, stream>>>(nxT, sumexp);
    // 6. diag_sm
    k_diagsm<<<dim3(13, 32), 256, 0, stream>>>(x1, invn, sumexp, dsm);
    // 7. xx = norm * (W_dc @ nx)  (MFMA, M=64)
    k_gemm_cm<4, 8, 1><<<dim3(7, 32), 256, 0, stream>>>(Wbf + 131072, nxT, xx, nrm);
    // 8. agg = mean of 3 dilated dwconvs (512 blocks, 2 spatial halves)
    k_dwconv<<<512, 448, 0, stream>>>(xx, Wsa1, Wsa2, Wsa3, agg);
    // 9. aggT = bf16 transpose of agg
    k_xpose64<<<dim3(49, 32), 256, 0, stream>>>(agg, aggT);
    // 10. fsT = bf16( relu(W_back @ aggT) * feats )  (K=64 MFMA, fused epilogue)
    k_gemm_fs<<<dim3(7, 32), 256, 0, stream>>>(Wbf + 147456, aggT, x1, dsm, fsT);
    // 11. y = x + W_up2 @ fsT  (MFMA, residual) -> overwrite x1 buffer
    k_gemm_cm<16, 8, 2><<<dim3(7, 32), 256, 0, stream>>>(Wbf + 65536, fsT, x1, x);
    // 12. BN stats
    k_bnstats<<<256, 256, 0, stream>>>(x1, gamma, beta, stats);
    // 13. BN apply + relu -> out
    k_bnapply<<<2048, 256, 0, stream>>>(x1, stats, out);
}